// Round 12
// baseline (342.473 us; speedup 1.0000x reference)
//
#include <hip/hip_runtime.h>
#include <hip/hip_bf16.h>
#include <math.h>

#define NPTS 4096
#define DINF 26
#define LOG2E 1.44269504088896f
#define JSPL 4    // k5 j-split
#define JS2  8    // k1m/k2m/k4m j-split

typedef float f32x4v __attribute__((ext_vector_type(4)));
typedef __bf16 bf16x8v __attribute__((ext_vector_type(8)));
typedef unsigned short ushort_t;

__device__ __forceinline__ float ldb(const float* p, int i){ return p[i]; }
__device__ __forceinline__ float lk(float v){ return v >= 0.0f ? v : 0.2f*v; }
__device__ __forceinline__ float wsum64(float v){
#pragma unroll
  for(int o=32;o>0;o>>=1) v += __shfl_down(v,o);
  return v;
}
__device__ __forceinline__ unsigned short f2bf(float f){
  return __builtin_bit_cast(unsigned short, __float2bfloat16(f));
}
__device__ __forceinline__ float bf2f(unsigned short u){
  return __bfloat162float(__builtin_bit_cast(__hip_bfloat16, u));
}
__device__ __forceinline__ void tangent(float nx,float ny,float nz,float* t1,float* t2){
  float s = (nz >= 0.0f) ? 1.0f : -1.0f;
  float a = -1.0f/(s+nz);
  float b = nx*ny*a;
  t1[0]=1.0f+s*nx*nx*a; t1[1]=s*b; t1[2]=-s*nx;
  t2[0]=b; t2[1]=s+ny*ny*a; t2[2]=-ny;
}

// ---- k0: convert + F1 hi/lo + vq4 + pn8 (merged k0+kF) ---------------------
__global__ __launch_bounds__(256) void k0_convert(const float* __restrict__ verts,
                                                  const float* __restrict__ vnorm,
                                                  const float* __restrict__ x,
                                                  float* __restrict__ vertsF,
                                                  float* __restrict__ nF,
                                                  float* __restrict__ pF,
                                                  float* __restrict__ xfF,
                                                  ushort_t* __restrict__ F1h,
                                                  ushort_t* __restrict__ F1l,
                                                  float* __restrict__ vq4,
                                                  float* __restrict__ pn8){
  int i = blockIdx.x*blockDim.x + threadIdx.x;
  if(i >= NPTS) return;
  float vx=verts[i*3+0], vy=verts[i*3+1], vz=verts[i*3+2];
  float nx=vnorm[i*3+0], ny=vnorm[i*3+1], nz=vnorm[i*3+2];
  vertsF[i*3+0]=vx; vertsF[i*3+1]=vy; vertsF[i*3+2]=vz;
  nF[i*3+0]=nx; nF[i*3+1]=ny; nF[i*3+2]=nz;
  float px=vx*(1.0f/9.0f), py=vy*(1.0f/9.0f), pz=vz*(1.0f/9.0f);
  pF[i*3+0]=px; pF[i*3+1]=py; pF[i*3+2]=pz;
  *(float4*)(vq4 + i*4) = make_float4(vx,vy,vz, vx*vx+vy*vy+vz*vz);
  *(float4*)(pn8 + i*8)     = make_float4(px,py,pz,0.0f);
  *(float4*)(pn8 + i*8 + 4) = make_float4(nx,ny,nz,0.0f);
  float fv[16];
  fv[0]=1.0f; fv[1]=vx; fv[2]=vy; fv[3]=vz;
  fv[4]=vx*vx; fv[5]=vx*vy; fv[6]=vx*vz; fv[7]=vy*vy; fv[8]=vy*vz; fv[9]=vz*vz;
  fv[10]=nx; fv[11]=ny; fv[12]=nz; fv[13]=0.0f; fv[14]=0.0f; fv[15]=0.0f;
#pragma unroll
  for(int c=0;c<16;c++){
    unsigned short h=f2bf(fv[c]);
    F1h[c*NPTS+i]=h;
    F1l[c*NPTS+i]=f2bf(fv[c]-bf2f(h));
  }
#pragma unroll
  for(int c=0;c<16;c++) xfF[i*DINF+c]=x[i*16+c];
}

// ---- k1m: pass-1 moments; fence-free (vq4 global), JS2 j-split -------------
__global__ __launch_bounds__(256) void k1m(const float* __restrict__ vertsF,
                                           const float* __restrict__ vq4,
                                           const ushort_t* __restrict__ F1h,
                                           const ushort_t* __restrict__ F1l,
                                           float* __restrict__ sc){
  __shared__ float red[4][16][16];
  const float c2e[5] = {0.5f*LOG2E, 0.125f*LOG2E, (1.0f/18.0f)*LOG2E,
                        0.02f*LOG2E, 0.005f*LOG2E};
  int lane = threadIdx.x & 63, w = threadIdx.x >> 6;
  int c16 = lane & 15, q = lane >> 4;
  int it = blockIdx.x >> 3, jseg = blockIdx.x & (JS2-1);
  int i0 = it*16;
  int ia = i0 + c16;
  float vix=vertsF[ia*3+0], viy=vertsF[ia*3+1], viz=vertsF[ia*3+2];
  float nsqi = vix*vix+viy*viy+viz*viz;
  f32x4v acc[5];
#pragma unroll
  for(int s=0;s<5;s++) acc[s] = (f32x4v){0.0f,0.0f,0.0f,0.0f};

  int jbeg = jseg*(NPTS/JS2) + w*(NPTS/JS2/4);
  int jend = jbeg + (NPTS/JS2/4);
#pragma unroll 1
  for(int jb=jbeg; jb<jend; jb+=64){
#pragma unroll
    for(int q2=0;q2<2;q2++){
      int rb = jb + q2*32 + q*8;
      bf16x8v bh = *(const bf16x8v*)(F1h + c16*NPTS + rb);
      bf16x8v bl = *(const bf16x8v*)(F1l + c16*NPTS + rb);
      bf16x8v af[5];
#pragma unroll
      for(int t=0;t<8;t++){
        float4 vv = *(const float4*)(vq4 + (rb+t)*4);
        float dot = vix*vv.x + viy*vv.y + viz*vv.z;
        float d2 = fmaxf(nsqi + vv.w - 2.0f*dot, 0.0f);
#pragma unroll
        for(int s=0;s<5;s++)
          af[s][t] = __builtin_bit_cast(__bf16, f2bf(exp2f(-d2*c2e[s])));
      }
#pragma unroll
      for(int s=0;s<5;s++){
        acc[s] = __builtin_amdgcn_mfma_f32_16x16x32_bf16(af[s], bh, acc[s], 0,0,0);
        acc[s] = __builtin_amdgcn_mfma_f32_16x16x32_bf16(af[s], bl, acc[s], 0,0,0);
      }
    }
  }
#pragma unroll
  for(int s=0;s<5;s++){
#pragma unroll
    for(int r=0;r<4;r++) red[w][q*4+r][c16] = acc[s][r];
    __syncthreads();
    if(w==0){
      float* base = sc + (size_t)s*13*NPTS;
#pragma unroll
      for(int r=0;r<4;r++){
        int m = q*4+r, i = i0+m;
        float D = red[0][m][c16]+red[1][m][c16]+red[2][m][c16]+red[3][m][c16];
        if(c16==0)       atomicAdd(&base[i], D);
        else if(c16<4)   atomicAdd(&base[NPTS + i*3 + (c16-1)], D);
        else if(c16<10)  atomicAdd(&base[4*NPTS + i*6 + (c16-4)], D);
        else if(c16<13)  atomicAdd(&base[10*NPTS + i*3 + (c16-10)], D);
      }
    }
    __syncthreads();
  }
}

// ---- k2p: precompute F2[s][c][j] hi/lo -------------------------------------
__global__ __launch_bounds__(256) void k2p(const float* __restrict__ vertsF,
                                           const float* __restrict__ sc,
                                           ushort_t* __restrict__ F2h,
                                           ushort_t* __restrict__ F2l){
  int idx = blockIdx.x*256 + threadIdx.x;
  int j = idx & (NPTS-1);
  int s = idx >> 12;
  float vx=vertsF[j*3+0], vy=vertsF[j*3+1], vz=vertsF[j*3+2];
  const float* ub = sc + (size_t)s*13*NPTS + 10*NPTS + (size_t)j*3;
  float ux=ub[0], uy=ub[1], uz=ub[2];
  float inv = 1.0f/fmaxf(sqrtf(ux*ux+uy*uy+uz*uz), 1e-12f);
  float n0=ux*inv, n1=uy*inv, n2=uz*inv;
  float fv[16];
  fv[0]=n0; fv[1]=n1; fv[2]=n2;
  fv[3]=vx*n0; fv[4]=vx*n1; fv[5]=vx*n2;
  fv[6]=vy*n0; fv[7]=vy*n1; fv[8]=vy*n2;
  fv[9]=vz*n0; fv[10]=vz*n1; fv[11]=vz*n2;
  fv[12]=0.0f; fv[13]=0.0f; fv[14]=0.0f; fv[15]=0.0f;
#pragma unroll
  for(int c=0;c<16;c++){
    unsigned short h=f2bf(fv[c]);
    F2h[((size_t)s*16+c)*NPTS+j]=h;
    F2l[((size_t)s*16+c)*NPTS+j]=f2bf(fv[c]-bf2f(h));
  }
}

// ---- k2m: pass-2 moments; fence-free, JS2 j-split --------------------------
__global__ __launch_bounds__(256) void k2m(const float* __restrict__ vertsF,
                                           const float* __restrict__ vq4,
                                           const ushort_t* __restrict__ F2h,
                                           const ushort_t* __restrict__ F2l,
                                           float* __restrict__ mom2){
  __shared__ float red[4][16][16];
  const float c2e[5] = {0.5f*LOG2E, 0.125f*LOG2E, (1.0f/18.0f)*LOG2E,
                        0.02f*LOG2E, 0.005f*LOG2E};
  int lane = threadIdx.x & 63, w = threadIdx.x >> 6;
  int c16 = lane & 15, q = lane >> 4;
  int it = blockIdx.x >> 3, jseg = blockIdx.x & (JS2-1);
  int i0 = it*16;
  int ia = i0 + c16;
  float vix=vertsF[ia*3+0], viy=vertsF[ia*3+1], viz=vertsF[ia*3+2];
  float nsqi = vix*vix+viy*viy+viz*viz;
  f32x4v acc[5];
#pragma unroll
  for(int s=0;s<5;s++) acc[s] = (f32x4v){0.0f,0.0f,0.0f,0.0f};

  int jbeg = jseg*(NPTS/JS2) + w*(NPTS/JS2/4);
  int jend = jbeg + (NPTS/JS2/4);
#pragma unroll 1
  for(int jb=jbeg; jb<jend; jb+=64){
#pragma unroll
    for(int q2=0;q2<2;q2++){
      int rb = jb + q2*32 + q*8;
      float d2t[8];
#pragma unroll
      for(int t=0;t<8;t++){
        float4 vv = *(const float4*)(vq4 + (rb+t)*4);
        float dot = vix*vv.x + viy*vv.y + viz*vv.z;
        d2t[t] = fmaxf(nsqi + vv.w - 2.0f*dot, 0.0f);
      }
#pragma unroll
      for(int s=0;s<5;s++){
        bf16x8v bh = *(const bf16x8v*)(F2h + ((size_t)s*16+c16)*NPTS + rb);
        bf16x8v bl = *(const bf16x8v*)(F2l + ((size_t)s*16+c16)*NPTS + rb);
        bf16x8v af;
#pragma unroll
        for(int t=0;t<8;t++)
          af[t] = __builtin_bit_cast(__bf16, f2bf(exp2f(-d2t[t]*c2e[s])));
        acc[s] = __builtin_amdgcn_mfma_f32_16x16x32_bf16(af, bh, acc[s], 0,0,0);
        acc[s] = __builtin_amdgcn_mfma_f32_16x16x32_bf16(af, bl, acc[s], 0,0,0);
      }
    }
  }
#pragma unroll
  for(int s=0;s<5;s++){
#pragma unroll
    for(int r=0;r<4;r++) red[w][q*4+r][c16] = acc[s][r];
    __syncthreads();
    if(w==0){
#pragma unroll
      for(int r=0;r<4;r++){
        int m = q*4+r, i = i0+m;
        float D = red[0][m][c16]+red[1][m][c16]+red[2][m][c16]+red[3][m][c16];
        if(c16<12) atomicAdd(&mom2[((size_t)s*NPTS + i)*12 + c16], D);
      }
    }
    __syncthreads();
  }
}

// ---- k2s: per-(i,scale) curvature solve ------------------------------------
__global__ __launch_bounds__(256) void k2s(const float* __restrict__ vertsF,
                                           const float* __restrict__ sc,
                                           const float* __restrict__ mom2,
                                           float* __restrict__ xfF){
  int idx = blockIdx.x*256 + threadIdx.x;
  int i = idx & (NPTS-1);
  int s = idx >> 12;
  const float* base = sc + (size_t)s*13*NPTS;
  float v[3] = { vertsF[i*3+0], vertsF[i*3+1], vertsF[i*3+2] };
  float s0 = base[i];
  float sx[3] = { base[NPTS+i*3+0], base[NPTS+i*3+1], base[NPTS+i*3+2] };
  float sxx6[6];
#pragma unroll
  for(int k=0;k<6;k++) sxx6[k]=base[4*NPTS+i*6+k];
  float ux=base[10*NPTS+i*3+0], uy=base[10*NPTS+i*3+1], uz=base[10*NPTS+i*3+2];
  float invn = 1.0f/fmaxf(sqrtf(ux*ux+uy*uy+uz*uz), 1e-12f);
  float nsi[3] = { ux*invn, uy*invn, uz*invn };
  const float* M2 = mom2 + ((size_t)s*NPTS + i)*12;
  float sn[3] = { M2[0], M2[1], M2[2] };
  float sxn[3][3];
#pragma unroll
  for(int a=0;a<3;a++)
#pragma unroll
    for(int b=0;b<3;b++) sxn[a][b]=M2[3+a*3+b];
  const int m6[3][3]={{0,1,2},{1,3,4},{2,4,5}};
  float cxx[3][3], cxn[3][3];
#pragma unroll
  for(int a=0;a<3;a++)
#pragma unroll
    for(int b=0;b<3;b++){
      cxx[a][b]=sxx6[m6[a][b]] - v[a]*sx[b] - sx[a]*v[b] + s0*v[a]*v[b];
      cxn[a][b]=sxn[a][b]    - v[a]*sn[b] - sx[a]*nsi[b] + s0*v[a]*nsi[b];
    }
  float t1[3],t2[3];
  tangent(nsi[0],nsi[1],nsi[2],t1,t2);
  float ppt[2][2], pqt[2][2];
#pragma unroll
  for(int k=0;k<2;k++){
    const float* tk = (k==0)?t1:t2;
#pragma unroll
    for(int l=0;l<2;l++){
      const float* tl = (l==0)?t1:t2;
      float accx=0.0f, accn=0.0f;
#pragma unroll
      for(int a=0;a<3;a++)
#pragma unroll
        for(int b=0;b<3;b++){
          accx += tk[a]*cxx[a][b]*tl[b];
          accn += tk[a]*cxn[a][b]*tl[b];
        }
      ppt[k][l]=accx + ((k==l)?0.01f:0.0f);
      pqt[k][l]=accn;
    }
  }
  float det = ppt[0][0]*ppt[1][1]-ppt[0][1]*ppt[1][0];
  float id = 1.0f/det;
  float S00=( ppt[1][1]*pqt[0][0]-ppt[0][1]*pqt[1][0])*id;
  float S01=( ppt[1][1]*pqt[0][1]-ppt[0][1]*pqt[1][1])*id;
  float S10=(-ppt[1][0]*pqt[0][0]+ppt[0][0]*pqt[1][0])*id;
  float S11=(-ppt[1][0]*pqt[0][1]+ppt[0][0]*pqt[1][1])*id;
  float f0=fminf(fmaxf(S00+S11,-1.0f),1.0f);
  float f1=fminf(fmaxf(S00*S11-S01*S10,-1.0f),1.0f);
  xfF[i*DINF+16+2*s]=f0;
  xfF[i*DINF+17+2*s]=f1;
}

// ---- k3 ----
__global__ __launch_bounds__(256) void k3_mlps(const float* __restrict__ xfF,
    const float* os_w1, const float* os_b1, const float* os_w2, const float* os_b2,
    const float* ni_w1, const float* ni_b1, const float* ni_w2, const float* ni_b2,
    float* __restrict__ wOS, float* __restrict__ hPre, float* __restrict__ stats){
  int i = blockIdx.x*256 + threadIdx.x;
  int lane = threadIdx.x & 63;
  float xf[DINF];
#pragma unroll
  for(int k=0;k<DINF;k++) xf[k]=xfF[i*DINF+k];
  float h1[16];
#pragma unroll
  for(int o=0;o<16;o++){
    float t=ldb(os_b1,o);
#pragma unroll
    for(int k=0;k<DINF;k++) t += xf[k]*ldb(os_w1,o*DINF+k);
    h1[o]=lk(t);
  }
  float w=ldb(os_b2,0);
#pragma unroll
  for(int o=0;o<16;o++) w += h1[o]*ldb(os_w2,o);
  wOS[i]=w;
#pragma unroll
  for(int o=0;o<16;o++){
    float t=ldb(ni_b1,o);
#pragma unroll
    for(int k=0;k<DINF;k++) t += xf[k]*ldb(ni_w1,o*DINF+k);
    h1[o]=lk(t);
  }
  float h2[16];
#pragma unroll
  for(int o=0;o<16;o++){
    float t=ldb(ni_b2,o);
#pragma unroll
    for(int k=0;k<16;k++) t += h1[k]*ldb(ni_w2,o*16+k);
    h2[o]=lk(t);
    hPre[i*16+o]=h2[o];
  }
  float gs[4]={0,0,0,0}, gq[4]={0,0,0,0};
#pragma unroll
  for(int c=0;c<16;c++){ gs[c>>2]+=h2[c]; gq[c>>2]+=h2[c]*h2[c]; }
  __shared__ float ls[8];
  if(threadIdx.x<8) ls[threadIdx.x]=0.0f;
  __syncthreads();
#pragma unroll
  for(int g=0;g<4;g++){ gs[g]=wsum64(gs[g]); gq[g]=wsum64(gq[g]); }
  if(lane==0){
#pragma unroll
    for(int g=0;g<4;g++){ atomicAdd(&ls[2*g],gs[g]); atomicAdd(&ls[2*g+1],gq[g]); }
  }
  __syncthreads();
  if(threadIdx.x<8) atomicAdd(&stats[threadIdx.x], ls[threadIdx.x]);
}

// ---- k3c: GN -> hTb  +  B4 hi/lo tables (merged kB) ------------------------
__global__ __launch_bounds__(256) void k3c_gn(const float* __restrict__ hPre,
                                              const float* __restrict__ stats,
                                              const float* gw, const float* gb,
                                              const float* __restrict__ pF,
                                              const float* __restrict__ wOS,
                                              ushort_t* __restrict__ hTb,
                                              ushort_t* __restrict__ B4h,
                                              ushort_t* __restrict__ B4l){
  int i = blockIdx.x*256 + threadIdx.x;
  float m[4], r[4];
#pragma unroll
  for(int g=0;g<4;g++){
    float mean = stats[2*g]*(1.0f/(4.0f*NPTS));
    float var  = stats[2*g+1]*(1.0f/(4.0f*NPTS)) - mean*mean;
    m[g]=mean; r[g]=1.0f/sqrtf(var+1e-5f);
  }
#pragma unroll
  for(int c=0;c<16;c++){
    int g=c>>2;
    float v=(hPre[i*16+c]-m[g])*r[g]*ldb(gw,c)+ldb(gb,c);
    hTb[c*NPTS+i]=f2bf(v);
  }
  float wj=wOS[i];
  float fv[16];
  fv[0]=wj*pF[i*3+0]; fv[1]=wj*pF[i*3+1]; fv[2]=wj*pF[i*3+2]; fv[3]=wj;
#pragma unroll
  for(int c=4;c<16;c++) fv[c]=0.0f;
#pragma unroll
  for(int c=0;c<16;c++){
    unsigned short h=f2bf(fv[c]);
    B4h[c*NPTS+i]=h;
    B4l[c*NPTS+i]=f2bf(fv[c]-bf2f(h));
  }
}

// ---- k4m: ov moments; fence-free, JS2 j-split, atomic partials -------------
__global__ __launch_bounds__(256) void k4m(const float* __restrict__ pF,
                                           const float* __restrict__ nF,
                                           const float* __restrict__ pn8,
                                           const ushort_t* __restrict__ B4h,
                                           const ushort_t* __restrict__ B4l,
                                           float* __restrict__ ov4){
  __shared__ float red[4][16][16];
  int lane = threadIdx.x & 63, w = threadIdx.x >> 6;
  int c16 = lane & 15, q = lane >> 4;
  int it = blockIdx.x >> 3, jseg = blockIdx.x & (JS2-1);
  int i0 = it*16;
  int ia = i0 + c16;
  float pix=pF[ia*3+0], piy=pF[ia*3+1], piz=pF[ia*3+2];
  float nix=nF[ia*3+0], niy=nF[ia*3+1], niz=nF[ia*3+2];
  f32x4v acc = {0.0f,0.0f,0.0f,0.0f};

  int jbeg = jseg*(NPTS/JS2) + w*(NPTS/JS2/4);
  int jend = jbeg + (NPTS/JS2/4);
#pragma unroll 1
  for(int jb=jbeg; jb<jend; jb+=64){
#pragma unroll
    for(int q2=0;q2<2;q2++){
      int rb = jb + q2*32 + q*8;
      bf16x8v bh = *(const bf16x8v*)(B4h + c16*NPTS + rb);
      bf16x8v bl = *(const bf16x8v*)(B4l + c16*NPTS + rb);
      bf16x8v af;
#pragma unroll
      for(int t=0;t<8;t++){
        float4 P  = *(const float4*)(pn8 + (size_t)(rb+t)*8);
        float4 Nj = *(const float4*)(pn8 + (size_t)(rb+t)*8 + 4);
        float dx=P.x-pix, dy=P.y-piy, dz=P.z-piz;
        float d2=dx*dx+dy*dy+dz*dz;
        float f=2.0f-(Nj.x*nix+Nj.y*niy+Nj.z*niz);
        af[t]=__builtin_bit_cast(__bf16, f2bf(exp2f(-d2*f*f*LOG2E)));
      }
      acc = __builtin_amdgcn_mfma_f32_16x16x32_bf16(af, bh, acc, 0,0,0);
      acc = __builtin_amdgcn_mfma_f32_16x16x32_bf16(af, bl, acc, 0,0,0);
    }
  }
#pragma unroll
  for(int r=0;r<4;r++) red[w][q*4+r][c16]=acc[r];
  __syncthreads();
  if(w==0){
#pragma unroll
    for(int r=0;r<4;r++){
      int m = q*4+r, i = i0+m;
      float D = red[0][m][c16]+red[1][m][c16]+red[2][m][c16]+red[3][m][c16];
      if(c16<4) atomicAdd(&ov4[i*4+c16], D);
    }
  }
}

// ---- k4s: finalize nuv from ov4 --------------------------------------------
__global__ __launch_bounds__(256) void k4s(const float* __restrict__ pF,
                                           const float* __restrict__ nF,
                                           const float* __restrict__ ov4,
                                           float* __restrict__ nuvF){
  int i = blockIdx.x*256 + threadIdx.x;
  float a0=ov4[i*4+0], a1=ov4[i*4+1], a2=ov4[i*4+2], a3=ov4[i*4+3];
  float pix=pF[i*3+0], piy=pF[i*3+1], piz=pF[i*3+2];
  float nix=nF[i*3+0], niy=nF[i*3+1], niz=nF[i*3+2];
  float o0=a0-a3*pix, o1=a1-a3*piy, o2=a2-a3*piz;
  float t1[3],t2[3];
  tangent(nix,niy,niz,t1,t2);
  float ov0=t1[0]*o0+t1[1]*o1+t1[2]*o2+1e-5f;
  float ov1=t2[0]*o0+t2[1]*o1+t2[2]*o2+1e-5f;
  float inv=1.0f/sqrtf(ov0*ov0+ov1*ov1);
  float ex=ov0*inv, ey=ov1*inv;
  nuvF[i*9+0]=nix; nuvF[i*9+1]=niy; nuvF[i*9+2]=niz;
  nuvF[i*9+3]= ex*t1[0]+ey*t2[0]; nuvF[i*9+4]= ex*t1[1]+ey*t2[1]; nuvF[i*9+5]= ex*t1[2]+ey*t2[2];
  nuvF[i*9+6]=-ey*t1[0]+ex*t2[0]; nuvF[i*9+7]=-ey*t1[1]+ex*t2[1]; nuvF[i*9+8]=-ey*t1[2]+ex*t2[2];
}

// ---- k5: conv, i-as-M; fence-free (pn8 global) -----------------------------
__global__ __launch_bounds__(256) void k5_conv(const float* __restrict__ pF,
                                               const float* __restrict__ pn8,
                                               const float* __restrict__ nuvF,
                                               const ushort_t* __restrict__ hTb,
                                               const float* cv_a1, const float* cv_b1,
                                               const float* cv_a2, const float* cv_b2,
                                               float* __restrict__ xiP){
  __shared__ float red[4][64][4];
  int lane = threadIdx.x & 63, w = threadIdx.x >> 6;
  int c16 = lane & 15, q = lane >> 4;
  int it = blockIdx.x >> 2, jseg = blockIdx.x & (JSPL-1);
  int i0 = it*16;
  int i = i0 + c16;
  float pix=pF[i*3+0], piy=pF[i*3+1], piz=pF[i*3+2];
  float nu[9];
#pragma unroll
  for(int k=0;k<9;k++) nu[k]=nuvF[i*9+k];
  float a1w[8][3], b1w[8];
#pragma unroll
  for(int c=0;c<8;c++){
    a1w[c][0]=cv_a1[c*3+0]; a1w[c][1]=cv_a1[c*3+1]; a1w[c][2]=cv_a1[c*3+2];
    b1w[c]=cv_b1[c];
  }
  f32x4v acc[9];
#pragma unroll
  for(int c=0;c<9;c++) acc[c]=(f32x4v){0.0f,0.0f,0.0f,0.0f};

  int jbeg = jseg*(NPTS/JSPL) + w*(NPTS/JSPL/4);
  int jend = jbeg + (NPTS/JSPL/4);
#pragma unroll 1
  for(int jb=jbeg; jb<jend; jb+=64){
#pragma unroll
    for(int q2=0;q2<2;q2++){
      int rb = jb + q2*32 + q*8;
      bf16x8v bfr = *(const bf16x8v*)(hTb + c16*NPTS + rb);
      bf16x8v af[9];
#pragma unroll
      for(int t=0;t<8;t++){
        float4 P  = *(const float4*)(pn8 + (size_t)(rb+t)*8);
        float4 Nj = *(const float4*)(pn8 + (size_t)(rb+t)*8 + 4);
        float dx=P.x-pix, dy=P.y-piy, dz=P.z-piz;
        float d2=dx*dx+dy*dy+dz*dz;
        float f=2.0f-(Nj.x*nu[0]+Nj.y*nu[1]+Nj.z*nu[2]);
        float win=exp2f(-d2*f*f*LOG2E);
        float X0=nu[0]*dx+nu[1]*dy+nu[2]*dz;
        float X1=nu[3]*dx+nu[4]*dy+nu[5]*dz;
        float X2=nu[6]*dx+nu[7]*dy+nu[8]*dz;
#pragma unroll
        for(int c=0;c<8;c++){
          float r=fmaf(X0,a1w[c][0],fmaf(X1,a1w[c][1],fmaf(X2,a1w[c][2],b1w[c])));
          af[c][t]=__builtin_bit_cast(__bf16, f2bf(win*fmaxf(r,0.0f)));
        }
        af[8][t]=__builtin_bit_cast(__bf16, f2bf(win));
      }
#pragma unroll
      for(int c=0;c<9;c++)
        acc[c] = __builtin_amdgcn_mfma_f32_16x16x32_bf16(af[c], bfr, acc[c], 0,0,0);
    }
  }
  float a2row[8];
#pragma unroll
  for(int c=0;c<8;c++) a2row[c]=cv_a2[c16*8+c];
  float b2v = cv_b2[c16];
#pragma unroll
  for(int r=0;r<4;r++){
    float xi = acc[8][r]*b2v;
#pragma unroll
    for(int c=0;c<8;c++) xi += acc[c][r]*a2row[c];
    red[w][lane][r]=xi;
  }
  __syncthreads();
  if(w==0){
#pragma unroll
    for(int r=0;r<4;r++){
      float v = red[0][lane][r]+red[1][lane][r]+red[2][lane][r]+red[3][lane][r];
      xiP[((size_t)jseg*NPTS + (i0 + q*4 + r))*16 + c16] = v;
    }
  }
}

// ---- k6a: sum xiP slices + no-MLP + GN-out stats ---------------------------
__global__ __launch_bounds__(256) void k6a(const float* __restrict__ xiP,
    const float* no_w1, const float* no_b1, const float* no_w2, const float* no_b2,
    float* __restrict__ tF, float* __restrict__ stats2){
  int i = blockIdx.x*256 + threadIdx.x;
  int lane = threadIdx.x & 63;
  float xi[16];
#pragma unroll
  for(int k=0;k<16;k++){
    float v=0.0f;
#pragma unroll
    for(int s=0;s<JSPL;s++) v += xiP[((size_t)s*NPTS + i)*16 + k];
    xi[k]=v;
  }
  float t1[16];
#pragma unroll
  for(int o=0;o<16;o++){
    float t=ldb(no_b1,o);
#pragma unroll
    for(int k=0;k<16;k++) t += xi[k]*ldb(no_w1,o*16+k);
    t1[o]=lk(t);
  }
  float t2[16];
#pragma unroll
  for(int o=0;o<16;o++){
    float t=ldb(no_b2,o);
#pragma unroll
    for(int k=0;k<16;k++) t += t1[k]*ldb(no_w2,o*16+k);
    t2[o]=lk(t);
    tF[i*16+o]=t2[o];
  }
  float gs[4]={0,0,0,0}, gq[4]={0,0,0,0};
#pragma unroll
  for(int c=0;c<16;c++){ gs[c>>2]+=t2[c]; gq[c>>2]+=t2[c]*t2[c]; }
  __shared__ float ls[8];
  if(threadIdx.x<8) ls[threadIdx.x]=0.0f;
  __syncthreads();
#pragma unroll
  for(int g=0;g<4;g++){ gs[g]=wsum64(gs[g]); gq[g]=wsum64(gq[g]); }
  if(lane==0){
#pragma unroll
    for(int g=0;g<4;g++){ atomicAdd(&ls[2*g],gs[g]); atomicAdd(&ls[2*g+1],gq[g]); }
  }
  __syncthreads();
  if(threadIdx.x<8) atomicAdd(&stats2[threadIdx.x], ls[threadIdx.x]);
}

// ---- k6c ----
__global__ __launch_bounds__(256) void k6c(const float* __restrict__ tF,
    const float* __restrict__ xfF, const float* __restrict__ stats2,
    const float* gw, const float* gb,
    const float* ll_w1, const float* ll_b1, const float* ll_w2, const float* ll_b2,
    const float* lt_w, const float* lt_b,
    float* __restrict__ out){
  int i = blockIdx.x*256 + threadIdx.x;
  float m[4], r[4];
#pragma unroll
  for(int g=0;g<4;g++){
    float mean = stats2[2*g]*(1.0f/(4.0f*NPTS));
    float var  = stats2[2*g+1]*(1.0f/(4.0f*NPTS)) - mean*mean;
    m[g]=mean; r[g]=1.0f/sqrtf(var+1e-5f);
  }
  float tn[16];
#pragma unroll
  for(int c=0;c<16;c++){
    int g=c>>2;
    tn[c]=(tF[i*16+c]-m[g])*r[g]*ldb(gw,c)+ldb(gb,c);
  }
  float z1[16];
#pragma unroll
  for(int o=0;o<16;o++){
    float t=ldb(ll_b1,o);
#pragma unroll
    for(int k=0;k<16;k++) t += tn[k]*ldb(ll_w1,o*16+k);
    z1[o]=fmaxf(t,0.0f);
  }
  float xf[DINF];
#pragma unroll
  for(int k=0;k<DINF;k++) xf[k]=xfF[i*DINF+k];
#pragma unroll
  for(int o=0;o<16;o++){
    float z=ldb(ll_b2,o);
#pragma unroll
    for(int k=0;k<16;k++) z += z1[k]*ldb(ll_w2,o*16+k);
    float lt=ldb(lt_b,o);
#pragma unroll
    for(int k=0;k<DINF;k++) lt += xf[k]*ldb(lt_w,o*DINF+k);
    out[i*16+o]=z+lt;
  }
}

extern "C" void kernel_launch(void* const* d_in, const int* in_sizes, int n_in,
                              void* d_out, int out_size, void* d_ws, size_t ws_size,
                              hipStream_t stream){
  const float* verts    = (const float*)d_in[0];
  const float* vnormals = (const float*)d_in[1];
  const float* x        = (const float*)d_in[2];
  const float* os_w1    = (const float*)d_in[3];
  const float* os_b1    = (const float*)d_in[4];
  const float* os_w2    = (const float*)d_in[5];
  const float* os_b2    = (const float*)d_in[6];
  const float* ni_w1    = (const float*)d_in[7];
  const float* ni_b1    = (const float*)d_in[8];
  const float* ni_w2    = (const float*)d_in[9];
  const float* ni_b2    = (const float*)d_in[10];
  const float* gn_in_w  = (const float*)d_in[11];
  const float* gn_in_b  = (const float*)d_in[12];
  const float* cv_a1    = (const float*)d_in[13];
  const float* cv_b1    = (const float*)d_in[14];
  const float* cv_a2    = (const float*)d_in[15];
  const float* cv_b2    = (const float*)d_in[16];
  const float* no_w1    = (const float*)d_in[17];
  const float* no_b1    = (const float*)d_in[18];
  const float* no_w2    = (const float*)d_in[19];
  const float* no_b2    = (const float*)d_in[20];
  const float* gn_out_w = (const float*)d_in[21];
  const float* gn_out_b = (const float*)d_in[22];
  const float* ll_w1    = (const float*)d_in[23];
  const float* ll_b1    = (const float*)d_in[24];
  const float* ll_w2    = (const float*)d_in[25];
  const float* ll_b2    = (const float*)d_in[26];
  const float* lt_w     = (const float*)d_in[27];
  const float* lt_b     = (const float*)d_in[28];

  float* W = (float*)d_ws;
  size_t off = 0;
  float* vertsF = W + off; off += (size_t)3*NPTS;
  float* nF     = W + off; off += (size_t)3*NPTS;
  float* pF     = W + off; off += (size_t)3*NPTS;
  float* xfF    = W + off; off += (size_t)DINF*NPTS;
  float* sc     = W + off; off += (size_t)13*NPTS*5;
  float* wOS    = W + off; off += (size_t)NPTS;
  float* hPre   = W + off; off += (size_t)16*NPTS;
  ushort_t* hTb = (ushort_t*)(W + off); off += (size_t)8*NPTS;
  float* nuvF   = W + off; off += (size_t)9*NPTS;
  float* xiP    = W + off; off += (size_t)JSPL*16*NPTS;
  float* tF     = W + off; off += (size_t)16*NPTS;
  float* stats  = W + off; off += 16;
  ushort_t* F1h = (ushort_t*)(W + off); off += (size_t)8*NPTS;
  ushort_t* F1l = (ushort_t*)(W + off); off += (size_t)8*NPTS;
  ushort_t* F2h = (ushort_t*)(W + off); off += (size_t)40*NPTS;
  ushort_t* F2l = (ushort_t*)(W + off); off += (size_t)40*NPTS;
  ushort_t* B4h = (ushort_t*)(W + off); off += (size_t)8*NPTS;
  ushort_t* B4l = (ushort_t*)(W + off); off += (size_t)8*NPTS;
  float* vq4    = W + off; off += (size_t)4*NPTS;
  float* pn8    = W + off; off += (size_t)8*NPTS;
  float* ov4    = W + off; off += (size_t)4*NPTS;
  float* mom2 = hPre;   // aliased: dead until k3 writes hPre; k2s done before k3

  hipMemsetAsync(stats, 0, 16*sizeof(float), stream);
  hipMemsetAsync(sc,   0, (size_t)13*NPTS*5*sizeof(float), stream);
  hipMemsetAsync(mom2, 0, (size_t)12*NPTS*5*sizeof(float), stream);
  hipMemsetAsync(ov4,  0, (size_t)4*NPTS*sizeof(float), stream);

  k0_convert<<<NPTS/256, 256, 0, stream>>>(verts, vnormals, x, vertsF, nF, pF, xfF,
                                           F1h, F1l, vq4, pn8);
  k1m<<<(NPTS/16)*JS2, 256, 0, stream>>>(vertsF, vq4, F1h, F1l, sc);
  k2p<<<5*NPTS/256, 256, 0, stream>>>(vertsF, sc, F2h, F2l);
  k2m<<<(NPTS/16)*JS2, 256, 0, stream>>>(vertsF, vq4, F2h, F2l, mom2);
  k2s<<<5*NPTS/256, 256, 0, stream>>>(vertsF, sc, mom2, xfF);
  k3_mlps<<<NPTS/256, 256, 0, stream>>>(xfF, os_w1, os_b1, os_w2, os_b2,
                                        ni_w1, ni_b1, ni_w2, ni_b2, wOS, hPre, stats);
  k3c_gn<<<NPTS/256, 256, 0, stream>>>(hPre, stats, gn_in_w, gn_in_b,
                                       pF, wOS, hTb, B4h, B4l);
  k4m<<<(NPTS/16)*JS2, 256, 0, stream>>>(pF, nF, pn8, B4h, B4l, ov4);
  k4s<<<NPTS/256, 256, 0, stream>>>(pF, nF, ov4, nuvF);
  k5_conv<<<(NPTS/16)*JSPL, 256, 0, stream>>>(pF, pn8, nuvF, hTb,
                                              cv_a1, cv_b1, cv_a2, cv_b2, xiP);
  k6a<<<NPTS/256, 256, 0, stream>>>(xiP, no_w1, no_b1, no_w2, no_b2, tF, stats+8);
  k6c<<<NPTS/256, 256, 0, stream>>>(tF, xfF, stats+8, gn_out_w, gn_out_b,
                                    ll_w1, ll_b1, ll_w2, ll_b2, lt_w, lt_b, (float*)d_out);
}

// Round 13
// 296.758 us; speedup vs baseline: 1.1541x; 1.1541x over previous
//
#include <hip/hip_runtime.h>
#include <hip/hip_bf16.h>
#include <math.h>

#define NPTS 4096
#define DINF 26
#define LOG2E 1.44269504088896f
#define JSPL 4    // k1m/k5 j-split
#define JS2  8    // k2m j-split (32-i tiles)

typedef float f32x4v __attribute__((ext_vector_type(4)));
typedef __bf16 bf16x8v __attribute__((ext_vector_type(8)));
typedef unsigned short ushort_t;

__device__ __forceinline__ float ldb(const float* p, int i){ return p[i]; }
__device__ __forceinline__ float lk(float v){ return v >= 0.0f ? v : 0.2f*v; }
__device__ __forceinline__ float wsum64(float v){
#pragma unroll
  for(int o=32;o>0;o>>=1) v += __shfl_down(v,o);
  return v;
}
__device__ __forceinline__ unsigned short f2bf(float f){
  return __builtin_bit_cast(unsigned short, __float2bfloat16(f));
}
__device__ __forceinline__ float bf2f(unsigned short u){
  return __bfloat162float(__builtin_bit_cast(__hip_bfloat16, u));
}
__device__ __forceinline__ void wave_lds_fence(){
  __builtin_amdgcn_wave_barrier();
  __builtin_amdgcn_s_waitcnt(0xC07F);   // lgkmcnt(0)
  __builtin_amdgcn_wave_barrier();
}
__device__ __forceinline__ void tangent(float nx,float ny,float nz,float* t1,float* t2){
  float s = (nz >= 0.0f) ? 1.0f : -1.0f;
  float a = -1.0f/(s+nz);
  float b = nx*ny*a;
  t1[0]=1.0f+s*nx*nx*a; t1[1]=s*b; t1[2]=-s*nx;
  t2[0]=b; t2[1]=s+ny*ny*a; t2[2]=-ny;
}

// ---- k0: convert + F1 hi/lo tables (merged kF) -----------------------------
__global__ __launch_bounds__(256) void k0_convert(const float* __restrict__ verts,
                                                  const float* __restrict__ vnorm,
                                                  const float* __restrict__ x,
                                                  float* __restrict__ vertsF,
                                                  float* __restrict__ nF,
                                                  float* __restrict__ pF,
                                                  float* __restrict__ xfF,
                                                  ushort_t* __restrict__ F1h,
                                                  ushort_t* __restrict__ F1l){
  int i = blockIdx.x*blockDim.x + threadIdx.x;
  if(i >= NPTS) return;
  float vx=verts[i*3+0], vy=verts[i*3+1], vz=verts[i*3+2];
  float nx=vnorm[i*3+0], ny=vnorm[i*3+1], nz=vnorm[i*3+2];
  vertsF[i*3+0]=vx; vertsF[i*3+1]=vy; vertsF[i*3+2]=vz;
  nF[i*3+0]=nx; nF[i*3+1]=ny; nF[i*3+2]=nz;
  pF[i*3+0]=vx*(1.0f/9.0f); pF[i*3+1]=vy*(1.0f/9.0f); pF[i*3+2]=vz*(1.0f/9.0f);
  float fv[16];
  fv[0]=1.0f; fv[1]=vx; fv[2]=vy; fv[3]=vz;
  fv[4]=vx*vx; fv[5]=vx*vy; fv[6]=vx*vz; fv[7]=vy*vy; fv[8]=vy*vz; fv[9]=vz*vz;
  fv[10]=nx; fv[11]=ny; fv[12]=nz; fv[13]=0.0f; fv[14]=0.0f; fv[15]=0.0f;
#pragma unroll
  for(int c=0;c<16;c++){
    unsigned short h=f2bf(fv[c]);
    F1h[c*NPTS+i]=h;
    F1l[c*NPTS+i]=f2bf(fv[c]-bf2f(h));
  }
#pragma unroll
  for(int c=0;c<16;c++) xfF[i*DINF+c]=x[i*16+c];
}

// ---- k1m: pass-1 moments (R11 form: vq LDS staging, F1 global) -------------
__global__ __launch_bounds__(256) void k1m(const float* __restrict__ vertsF,
                                           const ushort_t* __restrict__ F1h,
                                           const ushort_t* __restrict__ F1l,
                                           float* __restrict__ sc){
  __shared__ __align__(16) float vq[4][64][4];
  __shared__ float red[4][16][16];
  const float c2e[5] = {0.5f*LOG2E, 0.125f*LOG2E, (1.0f/18.0f)*LOG2E,
                        0.02f*LOG2E, 0.005f*LOG2E};
  int lane = threadIdx.x & 63, w = threadIdx.x >> 6;
  int c16 = lane & 15, q = lane >> 4;
  int it = blockIdx.x >> 2, jseg = blockIdx.x & (JSPL-1);
  int i0 = it*16;
  int ia = i0 + c16;
  float vix=vertsF[ia*3+0], viy=vertsF[ia*3+1], viz=vertsF[ia*3+2];
  float nsqi = vix*vix+viy*viy+viz*viz;
  f32x4v acc[5];
#pragma unroll
  for(int s=0;s<5;s++) acc[s] = (f32x4v){0.0f,0.0f,0.0f,0.0f};

  int jbeg = jseg*(NPTS/JSPL) + w*(NPTS/JSPL/4);
  int jend = jbeg + (NPTS/JSPL/4);
#pragma unroll 1
  for(int jb=jbeg; jb<jend; jb+=64){
    int j = jb + lane;
    float vx=vertsF[j*3+0], vy=vertsF[j*3+1], vz=vertsF[j*3+2];
    *(float4*)&vq[w][lane][0] = make_float4(vx,vy,vz,vx*vx+vy*vy+vz*vz);
    wave_lds_fence();
#pragma unroll
    for(int q2=0;q2<2;q2++){
      int rb = jb + q2*32 + q*8;
      bf16x8v bh = *(const bf16x8v*)(F1h + c16*NPTS + rb);
      bf16x8v bl = *(const bf16x8v*)(F1l + c16*NPTS + rb);
      bf16x8v af[5];
#pragma unroll
      for(int t=0;t<8;t++){
        float4 vv = *(const float4*)&vq[w][q2*32+q*8+t][0];
        float dot = vix*vv.x + viy*vv.y + viz*vv.z;
        float d2 = fmaxf(nsqi + vv.w - 2.0f*dot, 0.0f);
#pragma unroll
        for(int s=0;s<5;s++)
          af[s][t] = __builtin_bit_cast(__bf16, f2bf(exp2f(-d2*c2e[s])));
      }
#pragma unroll
      for(int s=0;s<5;s++){
        acc[s] = __builtin_amdgcn_mfma_f32_16x16x32_bf16(af[s], bh, acc[s], 0,0,0);
        acc[s] = __builtin_amdgcn_mfma_f32_16x16x32_bf16(af[s], bl, acc[s], 0,0,0);
      }
    }
    wave_lds_fence();
  }
#pragma unroll
  for(int s=0;s<5;s++){
#pragma unroll
    for(int r=0;r<4;r++) red[w][q*4+r][c16] = acc[s][r];
    __syncthreads();
    if(w==0){
      float* base = sc + (size_t)s*13*NPTS;
#pragma unroll
      for(int r=0;r<4;r++){
        int m = q*4+r, i = i0+m;
        float D = red[0][m][c16]+red[1][m][c16]+red[2][m][c16]+red[3][m][c16];
        if(c16==0)       atomicAdd(&base[i], D);
        else if(c16<4)   atomicAdd(&base[NPTS + i*3 + (c16-1)], D);
        else if(c16<10)  atomicAdd(&base[4*NPTS + i*6 + (c16-4)], D);
        else if(c16<13)  atomicAdd(&base[10*NPTS + i*3 + (c16-10)], D);
      }
    }
    __syncthreads();
  }
}

// ---- k2p: precompute F2[s][c][j] hi/lo -------------------------------------
__global__ __launch_bounds__(256) void k2p(const float* __restrict__ vertsF,
                                           const float* __restrict__ sc,
                                           ushort_t* __restrict__ F2h,
                                           ushort_t* __restrict__ F2l){
  int idx = blockIdx.x*256 + threadIdx.x;
  int j = idx & (NPTS-1);
  int s = idx >> 12;
  float vx=vertsF[j*3+0], vy=vertsF[j*3+1], vz=vertsF[j*3+2];
  const float* ub = sc + (size_t)s*13*NPTS + 10*NPTS + (size_t)j*3;
  float ux=ub[0], uy=ub[1], uz=ub[2];
  float inv = 1.0f/fmaxf(sqrtf(ux*ux+uy*uy+uz*uz), 1e-12f);
  float n0=ux*inv, n1=uy*inv, n2=uz*inv;
  float fv[16];
  fv[0]=n0; fv[1]=n1; fv[2]=n2;
  fv[3]=vx*n0; fv[4]=vx*n1; fv[5]=vx*n2;
  fv[6]=vy*n0; fv[7]=vy*n1; fv[8]=vy*n2;
  fv[9]=vz*n0; fv[10]=vz*n1; fv[11]=vz*n2;
  fv[12]=0.0f; fv[13]=0.0f; fv[14]=0.0f; fv[15]=0.0f;
#pragma unroll
  for(int c=0;c<16;c++){
    unsigned short h=f2bf(fv[c]);
    F2h[((size_t)s*16+c)*NPTS+j]=h;
    F2l[((size_t)s*16+c)*NPTS+j]=f2bf(fv[c]-bf2f(h));
  }
}

// ---- k2m: pass-2 moments; 32-i tile (2 subtiles share B loads) -------------
__global__ __launch_bounds__(256) void k2m(const float* __restrict__ vertsF,
                                           const ushort_t* __restrict__ F2h,
                                           const ushort_t* __restrict__ F2l,
                                           float* __restrict__ mom2){
  __shared__ __align__(16) float vq[4][64][4];
  __shared__ float red[4][16][16];
  const float c2e[5] = {0.5f*LOG2E, 0.125f*LOG2E, (1.0f/18.0f)*LOG2E,
                        0.02f*LOG2E, 0.005f*LOG2E};
  int lane = threadIdx.x & 63, w = threadIdx.x >> 6;
  int c16 = lane & 15, q = lane >> 4;
  int it = blockIdx.x >> 3, jseg = blockIdx.x & (JS2-1);
  int iA = it*32 + c16, iB = iA + 16;
  float vax=vertsF[iA*3+0], vay=vertsF[iA*3+1], vaz=vertsF[iA*3+2];
  float nsqA = vax*vax+vay*vay+vaz*vaz;
  float vbx=vertsF[iB*3+0], vby=vertsF[iB*3+1], vbz=vertsF[iB*3+2];
  float nsqB = vbx*vbx+vby*vby+vbz*vbz;
  f32x4v accA[5], accB[5];
#pragma unroll
  for(int s=0;s<5;s++){
    accA[s] = (f32x4v){0.0f,0.0f,0.0f,0.0f};
    accB[s] = (f32x4v){0.0f,0.0f,0.0f,0.0f};
  }

  int jbeg = jseg*(NPTS/JS2) + w*(NPTS/JS2/4);
  int jend = jbeg + (NPTS/JS2/4);
#pragma unroll 1
  for(int jb=jbeg; jb<jend; jb+=64){
    int j = jb + lane;
    float vx=vertsF[j*3+0], vy=vertsF[j*3+1], vz=vertsF[j*3+2];
    *(float4*)&vq[w][lane][0] = make_float4(vx,vy,vz,vx*vx+vy*vy+vz*vz);
    wave_lds_fence();
#pragma unroll
    for(int q2=0;q2<2;q2++){
      int rb = jb + q2*32 + q*8;
      float d2A[8], d2B[8];
#pragma unroll
      for(int t=0;t<8;t++){
        float4 vv = *(const float4*)&vq[w][q2*32+q*8+t][0];
        float dotA = vax*vv.x + vay*vv.y + vaz*vv.z;
        float dotB = vbx*vv.x + vby*vv.y + vbz*vv.z;
        d2A[t] = fmaxf(nsqA + vv.w - 2.0f*dotA, 0.0f);
        d2B[t] = fmaxf(nsqB + vv.w - 2.0f*dotB, 0.0f);
      }
#pragma unroll
      for(int s=0;s<5;s++){
        bf16x8v bh = *(const bf16x8v*)(F2h + ((size_t)s*16+c16)*NPTS + rb);
        bf16x8v bl = *(const bf16x8v*)(F2l + ((size_t)s*16+c16)*NPTS + rb);
        bf16x8v afA, afB;
#pragma unroll
        for(int t=0;t<8;t++){
          afA[t] = __builtin_bit_cast(__bf16, f2bf(exp2f(-d2A[t]*c2e[s])));
          afB[t] = __builtin_bit_cast(__bf16, f2bf(exp2f(-d2B[t]*c2e[s])));
        }
        accA[s] = __builtin_amdgcn_mfma_f32_16x16x32_bf16(afA, bh, accA[s], 0,0,0);
        accA[s] = __builtin_amdgcn_mfma_f32_16x16x32_bf16(afA, bl, accA[s], 0,0,0);
        accB[s] = __builtin_amdgcn_mfma_f32_16x16x32_bf16(afB, bh, accB[s], 0,0,0);
        accB[s] = __builtin_amdgcn_mfma_f32_16x16x32_bf16(afB, bl, accB[s], 0,0,0);
      }
    }
    wave_lds_fence();
  }
#pragma unroll
  for(int sub=0; sub<2; sub++){
    int ibase = it*32 + sub*16;
#pragma unroll
    for(int s=0;s<5;s++){
#pragma unroll
      for(int r=0;r<4;r++) red[w][q*4+r][c16] = (sub ? accB[s][r] : accA[s][r]);
      __syncthreads();
      if(w==0){
#pragma unroll
        for(int r=0;r<4;r++){
          int m = q*4+r, i = ibase+m;
          float D = red[0][m][c16]+red[1][m][c16]+red[2][m][c16]+red[3][m][c16];
          if(c16<12) atomicAdd(&mom2[((size_t)s*NPTS + i)*12 + c16], D);
        }
      }
      __syncthreads();
    }
  }
}

// ---- k23: curvature solve (all 5 scales) + os/ni MLPs + GN-in stats --------
__global__ __launch_bounds__(256) void k23(const float* __restrict__ vertsF,
    const float* __restrict__ sc, const float* __restrict__ mom2,
    float* __restrict__ xfF,
    const float* os_w1, const float* os_b1, const float* os_w2, const float* os_b2,
    const float* ni_w1, const float* ni_b1, const float* ni_w2, const float* ni_b2,
    float* __restrict__ wOS, float* __restrict__ hPre, float* __restrict__ stats){
  int i = blockIdx.x*256 + threadIdx.x;
  int lane = threadIdx.x & 63;
  float xf[DINF];
#pragma unroll
  for(int k=0;k<16;k++) xf[k]=xfF[i*DINF+k];
  float v[3] = { vertsF[i*3+0], vertsF[i*3+1], vertsF[i*3+2] };
#pragma unroll 1
  for(int s=0;s<5;s++){
    const float* base = sc + (size_t)s*13*NPTS;
    float s0 = base[i];
    float sx[3] = { base[NPTS+i*3+0], base[NPTS+i*3+1], base[NPTS+i*3+2] };
    float sxx6[6];
#pragma unroll
    for(int k=0;k<6;k++) sxx6[k]=base[4*NPTS+i*6+k];
    float ux=base[10*NPTS+i*3+0], uy=base[10*NPTS+i*3+1], uz=base[10*NPTS+i*3+2];
    float invn = 1.0f/fmaxf(sqrtf(ux*ux+uy*uy+uz*uz), 1e-12f);
    float nsi[3] = { ux*invn, uy*invn, uz*invn };
    const float* M2 = mom2 + ((size_t)s*NPTS + i)*12;
    float sn[3] = { M2[0], M2[1], M2[2] };
    float sxn[3][3];
#pragma unroll
    for(int a=0;a<3;a++)
#pragma unroll
      for(int b=0;b<3;b++) sxn[a][b]=M2[3+a*3+b];
    const int m6[3][3]={{0,1,2},{1,3,4},{2,4,5}};
    float cxx[3][3], cxn[3][3];
#pragma unroll
    for(int a=0;a<3;a++)
#pragma unroll
      for(int b=0;b<3;b++){
        cxx[a][b]=sxx6[m6[a][b]] - v[a]*sx[b] - sx[a]*v[b] + s0*v[a]*v[b];
        cxn[a][b]=sxn[a][b]    - v[a]*sn[b] - sx[a]*nsi[b] + s0*v[a]*nsi[b];
      }
    float t1[3],t2[3];
    tangent(nsi[0],nsi[1],nsi[2],t1,t2);
    float ppt[2][2], pqt[2][2];
#pragma unroll
    for(int k=0;k<2;k++){
      const float* tk = (k==0)?t1:t2;
#pragma unroll
      for(int l=0;l<2;l++){
        const float* tl = (l==0)?t1:t2;
        float accx=0.0f, accn=0.0f;
#pragma unroll
        for(int a=0;a<3;a++)
#pragma unroll
          for(int b=0;b<3;b++){
            accx += tk[a]*cxx[a][b]*tl[b];
            accn += tk[a]*cxn[a][b]*tl[b];
          }
        ppt[k][l]=accx + ((k==l)?0.01f:0.0f);
        pqt[k][l]=accn;
      }
    }
    float det = ppt[0][0]*ppt[1][1]-ppt[0][1]*ppt[1][0];
    float id = 1.0f/det;
    float S00=( ppt[1][1]*pqt[0][0]-ppt[0][1]*pqt[1][0])*id;
    float S01=( ppt[1][1]*pqt[0][1]-ppt[0][1]*pqt[1][1])*id;
    float S10=(-ppt[1][0]*pqt[0][0]+ppt[0][0]*pqt[1][0])*id;
    float S11=(-ppt[1][0]*pqt[0][1]+ppt[0][0]*pqt[1][1])*id;
    float f0=fminf(fmaxf(S00+S11,-1.0f),1.0f);
    float f1=fminf(fmaxf(S00*S11-S01*S10,-1.0f),1.0f);
    xf[16+2*s]=f0; xf[17+2*s]=f1;
    xfF[i*DINF+16+2*s]=f0;
    xfF[i*DINF+17+2*s]=f1;
  }
  // --- MLPs (former k3) ---
  float h1[16];
#pragma unroll
  for(int o=0;o<16;o++){
    float t=ldb(os_b1,o);
#pragma unroll
    for(int k=0;k<DINF;k++) t += xf[k]*ldb(os_w1,o*DINF+k);
    h1[o]=lk(t);
  }
  float w=ldb(os_b2,0);
#pragma unroll
  for(int o=0;o<16;o++) w += h1[o]*ldb(os_w2,o);
  wOS[i]=w;
#pragma unroll
  for(int o=0;o<16;o++){
    float t=ldb(ni_b1,o);
#pragma unroll
    for(int k=0;k<DINF;k++) t += xf[k]*ldb(ni_w1,o*DINF+k);
    h1[o]=lk(t);
  }
  float h2[16];
#pragma unroll
  for(int o=0;o<16;o++){
    float t=ldb(ni_b2,o);
#pragma unroll
    for(int k=0;k<16;k++) t += h1[k]*ldb(ni_w2,o*16+k);
    h2[o]=lk(t);
    hPre[i*16+o]=h2[o];
  }
  float gs[4]={0,0,0,0}, gq[4]={0,0,0,0};
#pragma unroll
  for(int c=0;c<16;c++){ gs[c>>2]+=h2[c]; gq[c>>2]+=h2[c]*h2[c]; }
  __shared__ float ls[8];
  if(threadIdx.x<8) ls[threadIdx.x]=0.0f;
  __syncthreads();
#pragma unroll
  for(int g=0;g<4;g++){ gs[g]=wsum64(gs[g]); gq[g]=wsum64(gq[g]); }
  if(lane==0){
#pragma unroll
    for(int g=0;g<4;g++){ atomicAdd(&ls[2*g],gs[g]); atomicAdd(&ls[2*g+1],gq[g]); }
  }
  __syncthreads();
  if(threadIdx.x<8) atomicAdd(&stats[threadIdx.x], ls[threadIdx.x]);
}

// ---- k3c: GN -> hTb  +  B4 hi/lo tables ------------------------------------
__global__ __launch_bounds__(256) void k3c_gn(const float* __restrict__ hPre,
                                              const float* __restrict__ stats,
                                              const float* gw, const float* gb,
                                              const float* __restrict__ pF,
                                              const float* __restrict__ wOS,
                                              ushort_t* __restrict__ hTb,
                                              ushort_t* __restrict__ B4h,
                                              ushort_t* __restrict__ B4l){
  int i = blockIdx.x*256 + threadIdx.x;
  float m[4], r[4];
#pragma unroll
  for(int g=0;g<4;g++){
    float mean = stats[2*g]*(1.0f/(4.0f*NPTS));
    float var  = stats[2*g+1]*(1.0f/(4.0f*NPTS)) - mean*mean;
    m[g]=mean; r[g]=1.0f/sqrtf(var+1e-5f);
  }
#pragma unroll
  for(int c=0;c<16;c++){
    int g=c>>2;
    float v=(hPre[i*16+c]-m[g])*r[g]*ldb(gw,c)+ldb(gb,c);
    hTb[c*NPTS+i]=f2bf(v);
  }
  float wj=wOS[i];
  float fv[16];
  fv[0]=wj*pF[i*3+0]; fv[1]=wj*pF[i*3+1]; fv[2]=wj*pF[i*3+2]; fv[3]=wj;
#pragma unroll
  for(int c=4;c<16;c++) fv[c]=0.0f;
#pragma unroll
  for(int c=0;c<16;c++){
    unsigned short h=f2bf(fv[c]);
    B4h[c*NPTS+i]=h;
    B4l[c*NPTS+i]=f2bf(fv[c]-bf2f(h));
  }
}

// ---- k4m: ov via MFMA (R11 form: 512 threads, vq LDS staging) --------------
__global__ __launch_bounds__(512) void k4m(const float* __restrict__ pF,
                                           const float* __restrict__ nF,
                                           const ushort_t* __restrict__ B4h,
                                           const ushort_t* __restrict__ B4l,
                                           float* __restrict__ nuvF){
  __shared__ __align__(16) float vq[8][64][8];
  __shared__ float red[8][16][4];
  int lane = threadIdx.x & 63, w = threadIdx.x >> 6;
  int c16 = lane & 15, q = lane >> 4;
  int i0 = blockIdx.x*16;
  int ia = i0 + c16;
  float pix=pF[ia*3+0], piy=pF[ia*3+1], piz=pF[ia*3+2];
  float nix=nF[ia*3+0], niy=nF[ia*3+1], niz=nF[ia*3+2];
  f32x4v acc = {0.0f,0.0f,0.0f,0.0f};

#pragma unroll 1
  for(int jb=w*512; jb<w*512+512; jb+=64){
    int j = jb + lane;
    *(float4*)&vq[w][lane][0] = make_float4(pF[j*3+0],pF[j*3+1],pF[j*3+2],0.0f);
    *(float4*)&vq[w][lane][4] = make_float4(nF[j*3+0],nF[j*3+1],nF[j*3+2],0.0f);
    wave_lds_fence();
#pragma unroll
    for(int q2=0;q2<2;q2++){
      int rb = jb + q2*32 + q*8;
      bf16x8v bh = *(const bf16x8v*)(B4h + c16*NPTS + rb);
      bf16x8v bl = *(const bf16x8v*)(B4l + c16*NPTS + rb);
      bf16x8v af;
#pragma unroll
      for(int t=0;t<8;t++){
        float4 P  = *(const float4*)&vq[w][q2*32+q*8+t][0];
        float4 Nj = *(const float4*)&vq[w][q2*32+q*8+t][4];
        float dx=P.x-pix, dy=P.y-piy, dz=P.z-piz;
        float d2=dx*dx+dy*dy+dz*dz;
        float f=2.0f-(Nj.x*nix+Nj.y*niy+Nj.z*niz);
        af[t]=__builtin_bit_cast(__bf16, f2bf(exp2f(-d2*f*f*LOG2E)));
      }
      acc = __builtin_amdgcn_mfma_f32_16x16x32_bf16(af, bh, acc, 0,0,0);
      acc = __builtin_amdgcn_mfma_f32_16x16x32_bf16(af, bl, acc, 0,0,0);
    }
    wave_lds_fence();
  }
#pragma unroll
  for(int r=0;r<4;r++) if(c16<4) red[w][q*4+r][c16]=acc[r];
  __syncthreads();
  if(threadIdx.x<16){
    int tid=threadIdx.x, i=i0+tid;
    float a0=0,a1=0,a2=0,a3=0;
#pragma unroll
    for(int ww=0;ww<8;ww++){
      a0+=red[ww][tid][0]; a1+=red[ww][tid][1];
      a2+=red[ww][tid][2]; a3+=red[ww][tid][3];
    }
    float pix2=pF[i*3+0], piy2=pF[i*3+1], piz2=pF[i*3+2];
    float nix2=nF[i*3+0], niy2=nF[i*3+1], niz2=nF[i*3+2];
    float o0=a0-a3*pix2, o1=a1-a3*piy2, o2=a2-a3*piz2;
    float t1[3],t2[3];
    tangent(nix2,niy2,niz2,t1,t2);
    float ov0=t1[0]*o0+t1[1]*o1+t1[2]*o2+1e-5f;
    float ov1=t2[0]*o0+t2[1]*o1+t2[2]*o2+1e-5f;
    float inv=1.0f/sqrtf(ov0*ov0+ov1*ov1);
    float ex=ov0*inv, ey=ov1*inv;
    nuvF[i*9+0]=nix2; nuvF[i*9+1]=niy2; nuvF[i*9+2]=niz2;
    nuvF[i*9+3]= ex*t1[0]+ey*t2[0]; nuvF[i*9+4]= ex*t1[1]+ey*t2[1]; nuvF[i*9+5]= ex*t1[2]+ey*t2[2];
    nuvF[i*9+6]=-ey*t1[0]+ex*t2[0]; nuvF[i*9+7]=-ey*t1[1]+ex*t2[1]; nuvF[i*9+8]=-ey*t1[2]+ex*t2[2];
  }
}

// ---- k5: conv, i-as-M (R11 form: vq LDS staging) ---------------------------
__global__ __launch_bounds__(256) void k5_conv(const float* __restrict__ pF,
                                               const float* __restrict__ nF,
                                               const float* __restrict__ nuvF,
                                               const ushort_t* __restrict__ hTb,
                                               const float* cv_a1, const float* cv_b1,
                                               const float* cv_a2, const float* cv_b2,
                                               float* __restrict__ xiP){
  __shared__ __align__(16) float vq[4][64][8];
  __shared__ float red[4][64][4];
  int lane = threadIdx.x & 63, w = threadIdx.x >> 6;
  int c16 = lane & 15, q = lane >> 4;
  int it = blockIdx.x >> 2, jseg = blockIdx.x & (JSPL-1);
  int i0 = it*16;
  int i = i0 + c16;
  float pix=pF[i*3+0], piy=pF[i*3+1], piz=pF[i*3+2];
  float nu[9];
#pragma unroll
  for(int k=0;k<9;k++) nu[k]=nuvF[i*9+k];
  float a1w[8][3], b1w[8];
#pragma unroll
  for(int c=0;c<8;c++){
    a1w[c][0]=cv_a1[c*3+0]; a1w[c][1]=cv_a1[c*3+1]; a1w[c][2]=cv_a1[c*3+2];
    b1w[c]=cv_b1[c];
  }
  f32x4v acc[9];
#pragma unroll
  for(int c=0;c<9;c++) acc[c]=(f32x4v){0.0f,0.0f,0.0f,0.0f};

  int jbeg = jseg*(NPTS/JSPL) + w*(NPTS/JSPL/4);
  int jend = jbeg + (NPTS/JSPL/4);
#pragma unroll 1
  for(int jb=jbeg; jb<jend; jb+=64){
    int j = jb + lane;
    *(float4*)&vq[w][lane][0] = make_float4(pF[j*3+0],pF[j*3+1],pF[j*3+2],0.0f);
    *(float4*)&vq[w][lane][4] = make_float4(nF[j*3+0],nF[j*3+1],nF[j*3+2],0.0f);
    wave_lds_fence();
#pragma unroll
    for(int q2=0;q2<2;q2++){
      int rb = jb + q2*32 + q*8;
      bf16x8v bfr = *(const bf16x8v*)(hTb + c16*NPTS + rb);
      bf16x8v af[9];
#pragma unroll
      for(int t=0;t<8;t++){
        int rloc = q2*32 + q*8 + t;
        float4 P  = *(const float4*)&vq[w][rloc][0];
        float4 Nj = *(const float4*)&vq[w][rloc][4];
        float dx=P.x-pix, dy=P.y-piy, dz=P.z-piz;
        float d2=dx*dx+dy*dy+dz*dz;
        float f=2.0f-(Nj.x*nu[0]+Nj.y*nu[1]+Nj.z*nu[2]);
        float win=exp2f(-d2*f*f*LOG2E);
        float X0=nu[0]*dx+nu[1]*dy+nu[2]*dz;
        float X1=nu[3]*dx+nu[4]*dy+nu[5]*dz;
        float X2=nu[6]*dx+nu[7]*dy+nu[8]*dz;
#pragma unroll
        for(int c=0;c<8;c++){
          float r=fmaf(X0,a1w[c][0],fmaf(X1,a1w[c][1],fmaf(X2,a1w[c][2],b1w[c])));
          af[c][t]=__builtin_bit_cast(__bf16, f2bf(win*fmaxf(r,0.0f)));
        }
        af[8][t]=__builtin_bit_cast(__bf16, f2bf(win));
      }
#pragma unroll
      for(int c=0;c<9;c++)
        acc[c] = __builtin_amdgcn_mfma_f32_16x16x32_bf16(af[c], bfr, acc[c], 0,0,0);
    }
    wave_lds_fence();
  }
  float a2row[8];
#pragma unroll
  for(int c=0;c<8;c++) a2row[c]=cv_a2[c16*8+c];
  float b2v = cv_b2[c16];
#pragma unroll
  for(int r=0;r<4;r++){
    float xi = acc[8][r]*b2v;
#pragma unroll
    for(int c=0;c<8;c++) xi += acc[c][r]*a2row[c];
    red[w][lane][r]=xi;
  }
  __syncthreads();
  if(w==0){
#pragma unroll
    for(int r=0;r<4;r++){
      float v = red[0][lane][r]+red[1][lane][r]+red[2][lane][r]+red[3][lane][r];
      xiP[((size_t)jseg*NPTS + (i0 + q*4 + r))*16 + c16] = v;
    }
  }
}

// ---- k6a: sum xiP slices + no-MLP + GN-out stats ---------------------------
__global__ __launch_bounds__(256) void k6a(const float* __restrict__ xiP,
    const float* no_w1, const float* no_b1, const float* no_w2, const float* no_b2,
    float* __restrict__ tF, float* __restrict__ stats2){
  int i = blockIdx.x*256 + threadIdx.x;
  int lane = threadIdx.x & 63;
  float xi[16];
#pragma unroll
  for(int k=0;k<16;k++){
    float v=0.0f;
#pragma unroll
    for(int s=0;s<JSPL;s++) v += xiP[((size_t)s*NPTS + i)*16 + k];
    xi[k]=v;
  }
  float t1[16];
#pragma unroll
  for(int o=0;o<16;o++){
    float t=ldb(no_b1,o);
#pragma unroll
    for(int k=0;k<16;k++) t += xi[k]*ldb(no_w1,o*16+k);
    t1[o]=lk(t);
  }
  float t2[16];
#pragma unroll
  for(int o=0;o<16;o++){
    float t=ldb(no_b2,o);
#pragma unroll
    for(int k=0;k<16;k++) t += t1[k]*ldb(no_w2,o*16+k);
    t2[o]=lk(t);
    tF[i*16+o]=t2[o];
  }
  float gs[4]={0,0,0,0}, gq[4]={0,0,0,0};
#pragma unroll
  for(int c=0;c<16;c++){ gs[c>>2]+=t2[c]; gq[c>>2]+=t2[c]*t2[c]; }
  __shared__ float ls[8];
  if(threadIdx.x<8) ls[threadIdx.x]=0.0f;
  __syncthreads();
#pragma unroll
  for(int g=0;g<4;g++){ gs[g]=wsum64(gs[g]); gq[g]=wsum64(gq[g]); }
  if(lane==0){
#pragma unroll
    for(int g=0;g<4;g++){ atomicAdd(&ls[2*g],gs[g]); atomicAdd(&ls[2*g+1],gq[g]); }
  }
  __syncthreads();
  if(threadIdx.x<8) atomicAdd(&stats2[threadIdx.x], ls[threadIdx.x]);
}

// ---- k6c ----
__global__ __launch_bounds__(256) void k6c(const float* __restrict__ tF,
    const float* __restrict__ xfF, const float* __restrict__ stats2,
    const float* gw, const float* gb,
    const float* ll_w1, const float* ll_b1, const float* ll_w2, const float* ll_b2,
    const float* lt_w, const float* lt_b,
    float* __restrict__ out){
  int i = blockIdx.x*256 + threadIdx.x;
  float m[4], r[4];
#pragma unroll
  for(int g=0;g<4;g++){
    float mean = stats2[2*g]*(1.0f/(4.0f*NPTS));
    float var  = stats2[2*g+1]*(1.0f/(4.0f*NPTS)) - mean*mean;
    m[g]=mean; r[g]=1.0f/sqrtf(var+1e-5f);
  }
  float tn[16];
#pragma unroll
  for(int c=0;c<16;c++){
    int g=c>>2;
    tn[c]=(tF[i*16+c]-m[g])*r[g]*ldb(gw,c)+ldb(gb,c);
  }
  float z1[16];
#pragma unroll
  for(int o=0;o<16;o++){
    float t=ldb(ll_b1,o);
#pragma unroll
    for(int k=0;k<16;k++) t += tn[k]*ldb(ll_w1,o*16+k);
    z1[o]=fmaxf(t,0.0f);
  }
  float xf[DINF];
#pragma unroll
  for(int k=0;k<DINF;k++) xf[k]=xfF[i*DINF+k];
#pragma unroll
  for(int o=0;o<16;o++){
    float z=ldb(ll_b2,o);
#pragma unroll
    for(int k=0;k<16;k++) z += z1[k]*ldb(ll_w2,o*16+k);
    float lt=ldb(lt_b,o);
#pragma unroll
    for(int k=0;k<DINF;k++) lt += xf[k]*ldb(lt_w,o*DINF+k);
    out[i*16+o]=z+lt;
  }
}

extern "C" void kernel_launch(void* const* d_in, const int* in_sizes, int n_in,
                              void* d_out, int out_size, void* d_ws, size_t ws_size,
                              hipStream_t stream){
  const float* verts    = (const float*)d_in[0];
  const float* vnormals = (const float*)d_in[1];
  const float* x        = (const float*)d_in[2];
  const float* os_w1    = (const float*)d_in[3];
  const float* os_b1    = (const float*)d_in[4];
  const float* os_w2    = (const float*)d_in[5];
  const float* os_b2    = (const float*)d_in[6];
  const float* ni_w1    = (const float*)d_in[7];
  const float* ni_b1    = (const float*)d_in[8];
  const float* ni_w2    = (const float*)d_in[9];
  const float* ni_b2    = (const float*)d_in[10];
  const float* gn_in_w  = (const float*)d_in[11];
  const float* gn_in_b  = (const float*)d_in[12];
  const float* cv_a1    = (const float*)d_in[13];
  const float* cv_b1    = (const float*)d_in[14];
  const float* cv_a2    = (const float*)d_in[15];
  const float* cv_b2    = (const float*)d_in[16];
  const float* no_w1    = (const float*)d_in[17];
  const float* no_b1    = (const float*)d_in[18];
  const float* no_w2    = (const float*)d_in[19];
  const float* no_b2    = (const float*)d_in[20];
  const float* gn_out_w = (const float*)d_in[21];
  const float* gn_out_b = (const float*)d_in[22];
  const float* ll_w1    = (const float*)d_in[23];
  const float* ll_b1    = (const float*)d_in[24];
  const float* ll_w2    = (const float*)d_in[25];
  const float* ll_b2    = (const float*)d_in[26];
  const float* lt_w     = (const float*)d_in[27];
  const float* lt_b     = (const float*)d_in[28];

  float* W = (float*)d_ws;
  size_t off = 0;
  float* vertsF = W + off; off += (size_t)3*NPTS;
  float* nF     = W + off; off += (size_t)3*NPTS;
  float* pF     = W + off; off += (size_t)3*NPTS;
  float* xfF    = W + off; off += (size_t)DINF*NPTS;
  float* wOS    = W + off; off += (size_t)NPTS;
  float* hPre   = W + off; off += (size_t)16*NPTS;
  ushort_t* hTb = (ushort_t*)(W + off); off += (size_t)8*NPTS;
  float* nuvF   = W + off; off += (size_t)9*NPTS;
  float* xiP    = W + off; off += (size_t)JSPL*16*NPTS;
  float* tF     = W + off; off += (size_t)16*NPTS;
  ushort_t* F1h = (ushort_t*)(W + off); off += (size_t)8*NPTS;
  ushort_t* F1l = (ushort_t*)(W + off); off += (size_t)8*NPTS;
  ushort_t* F2h = (ushort_t*)(W + off); off += (size_t)40*NPTS;
  ushort_t* F2l = (ushort_t*)(W + off); off += (size_t)40*NPTS;
  ushort_t* B4h = (ushort_t*)(W + off); off += (size_t)8*NPTS;
  ushort_t* B4l = (ushort_t*)(W + off); off += (size_t)8*NPTS;
  // contiguous zero region: sc | mom2 | stats
  float* zr     = W + off;
  float* sc     = W + off; off += (size_t)13*NPTS*5;
  float* mom2   = W + off; off += (size_t)12*NPTS*5;
  float* stats  = W + off; off += 16;
  size_t zbytes = ((size_t)13*NPTS*5 + (size_t)12*NPTS*5 + 16)*sizeof(float);

  hipMemsetAsync(zr, 0, zbytes, stream);

  k0_convert<<<NPTS/256, 256, 0, stream>>>(verts, vnormals, x, vertsF, nF, pF, xfF,
                                           F1h, F1l);
  k1m<<<(NPTS/16)*JSPL, 256, 0, stream>>>(vertsF, F1h, F1l, sc);
  k2p<<<5*NPTS/256, 256, 0, stream>>>(vertsF, sc, F2h, F2l);
  k2m<<<(NPTS/32)*JS2, 256, 0, stream>>>(vertsF, F2h, F2l, mom2);
  k23<<<NPTS/256, 256, 0, stream>>>(vertsF, sc, mom2, xfF,
                                    os_w1, os_b1, os_w2, os_b2,
                                    ni_w1, ni_b1, ni_w2, ni_b2, wOS, hPre, stats);
  k3c_gn<<<NPTS/256, 256, 0, stream>>>(hPre, stats, gn_in_w, gn_in_b,
                                       pF, wOS, hTb, B4h, B4l);
  k4m<<<NPTS/16, 512, 0, stream>>>(pF, nF, B4h, B4l, nuvF);
  k5_conv<<<(NPTS/16)*JSPL, 256, 0, stream>>>(pF, nF, nuvF, hTb,
                                              cv_a1, cv_b1, cv_a2, cv_b2, xiP);
  k6a<<<NPTS/256, 256, 0, stream>>>(xiP, no_w1, no_b1, no_w2, no_b2, tF, stats+8);
  k6c<<<NPTS/256, 256, 0, stream>>>(tF, xfF, stats+8, gn_out_w, gn_out_b,
                                    ll_w1, ll_b1, ll_w2, ll_b2, lt_w, lt_b, (float*)d_out);
}

// Round 14
// 291.954 us; speedup vs baseline: 1.1730x; 1.0165x over previous
//
#include <hip/hip_runtime.h>
#include <hip/hip_bf16.h>
#include <math.h>

#define NPTS 4096
#define DINF 26
#define LOG2E 1.44269504088896f
#define JSPL 4    // k1m j-split
#define JS2  8    // k2m j-split (32-i tiles)
#define JK5  8    // k5 j-split

typedef float f32x4v __attribute__((ext_vector_type(4)));
typedef __bf16 bf16x8v __attribute__((ext_vector_type(8)));
typedef unsigned short ushort_t;

__device__ __forceinline__ float ldb(const float* p, int i){ return p[i]; }
__device__ __forceinline__ float lk(float v){ return v >= 0.0f ? v : 0.2f*v; }
__device__ __forceinline__ float wsum64(float v){
#pragma unroll
  for(int o=32;o>0;o>>=1) v += __shfl_down(v,o);
  return v;
}
__device__ __forceinline__ unsigned short f2bf(float f){
  return __builtin_bit_cast(unsigned short, __float2bfloat16(f));
}
__device__ __forceinline__ float bf2f(unsigned short u){
  return __bfloat162float(__builtin_bit_cast(__hip_bfloat16, u));
}
__device__ __forceinline__ void wave_lds_fence(){
  __builtin_amdgcn_wave_barrier();
  __builtin_amdgcn_s_waitcnt(0xC07F);   // lgkmcnt(0)
  __builtin_amdgcn_wave_barrier();
}
__device__ __forceinline__ void tangent(float nx,float ny,float nz,float* t1,float* t2){
  float s = (nz >= 0.0f) ? 1.0f : -1.0f;
  float a = -1.0f/(s+nz);
  float b = nx*ny*a;
  t1[0]=1.0f+s*nx*nx*a; t1[1]=s*b; t1[2]=-s*nx;
  t2[0]=b; t2[1]=s+ny*ny*a; t2[2]=-ny;
}

// ---- k0: convert + F1 hi/lo tables -----------------------------------------
__global__ __launch_bounds__(256) void k0_convert(const float* __restrict__ verts,
                                                  const float* __restrict__ vnorm,
                                                  const float* __restrict__ x,
                                                  float* __restrict__ vertsF,
                                                  float* __restrict__ nF,
                                                  float* __restrict__ pF,
                                                  float* __restrict__ xfF,
                                                  ushort_t* __restrict__ F1h,
                                                  ushort_t* __restrict__ F1l){
  int i = blockIdx.x*blockDim.x + threadIdx.x;
  if(i >= NPTS) return;
  float vx=verts[i*3+0], vy=verts[i*3+1], vz=verts[i*3+2];
  float nx=vnorm[i*3+0], ny=vnorm[i*3+1], nz=vnorm[i*3+2];
  vertsF[i*3+0]=vx; vertsF[i*3+1]=vy; vertsF[i*3+2]=vz;
  nF[i*3+0]=nx; nF[i*3+1]=ny; nF[i*3+2]=nz;
  pF[i*3+0]=vx*(1.0f/9.0f); pF[i*3+1]=vy*(1.0f/9.0f); pF[i*3+2]=vz*(1.0f/9.0f);
  float fv[16];
  fv[0]=1.0f; fv[1]=vx; fv[2]=vy; fv[3]=vz;
  fv[4]=vx*vx; fv[5]=vx*vy; fv[6]=vx*vz; fv[7]=vy*vy; fv[8]=vy*vz; fv[9]=vz*vz;
  fv[10]=nx; fv[11]=ny; fv[12]=nz; fv[13]=0.0f; fv[14]=0.0f; fv[15]=0.0f;
#pragma unroll
  for(int c=0;c<16;c++){
    unsigned short h=f2bf(fv[c]);
    F1h[c*NPTS+i]=h;
    F1l[c*NPTS+i]=f2bf(fv[c]-bf2f(h));
  }
#pragma unroll
  for(int c=0;c<16;c++) xfF[i*DINF+c]=x[i*16+c];
}

// ---- k1m: pass-1 moments (vq padded to 5) ----------------------------------
__global__ __launch_bounds__(256) void k1m(const float* __restrict__ vertsF,
                                           const ushort_t* __restrict__ F1h,
                                           const ushort_t* __restrict__ F1l,
                                           float* __restrict__ sc){
  __shared__ __align__(16) float vq[4][64][5];
  __shared__ float red[4][16][17];
  const float c2e[5] = {0.5f*LOG2E, 0.125f*LOG2E, (1.0f/18.0f)*LOG2E,
                        0.02f*LOG2E, 0.005f*LOG2E};
  int lane = threadIdx.x & 63, w = threadIdx.x >> 6;
  int c16 = lane & 15, q = lane >> 4;
  int it = blockIdx.x >> 2, jseg = blockIdx.x & (JSPL-1);
  int i0 = it*16;
  int ia = i0 + c16;
  float vix=vertsF[ia*3+0], viy=vertsF[ia*3+1], viz=vertsF[ia*3+2];
  float nsqi = vix*vix+viy*viy+viz*viz;
  f32x4v acc[5];
#pragma unroll
  for(int s=0;s<5;s++) acc[s] = (f32x4v){0.0f,0.0f,0.0f,0.0f};

  int jbeg = jseg*(NPTS/JSPL) + w*(NPTS/JSPL/4);
  int jend = jbeg + (NPTS/JSPL/4);
#pragma unroll 1
  for(int jb=jbeg; jb<jend; jb+=64){
    int j = jb + lane;
    float vx=vertsF[j*3+0], vy=vertsF[j*3+1], vz=vertsF[j*3+2];
    vq[w][lane][0]=vx; vq[w][lane][1]=vy; vq[w][lane][2]=vz;
    vq[w][lane][3]=vx*vx+vy*vy+vz*vz;
    wave_lds_fence();
#pragma unroll
    for(int q2=0;q2<2;q2++){
      int rb = jb + q2*32 + q*8;
      bf16x8v bh = *(const bf16x8v*)(F1h + c16*NPTS + rb);
      bf16x8v bl = *(const bf16x8v*)(F1l + c16*NPTS + rb);
      bf16x8v af[5];
#pragma unroll
      for(int t=0;t<8;t++){
        const float* vv = &vq[w][q2*32+q*8+t][0];
        float dot = vix*vv[0] + viy*vv[1] + viz*vv[2];
        float d2 = fmaxf(nsqi + vv[3] - 2.0f*dot, 0.0f);
#pragma unroll
        for(int s=0;s<5;s++)
          af[s][t] = __builtin_bit_cast(__bf16, f2bf(exp2f(-d2*c2e[s])));
      }
#pragma unroll
      for(int s=0;s<5;s++){
        acc[s] = __builtin_amdgcn_mfma_f32_16x16x32_bf16(af[s], bh, acc[s], 0,0,0);
        acc[s] = __builtin_amdgcn_mfma_f32_16x16x32_bf16(af[s], bl, acc[s], 0,0,0);
      }
    }
    wave_lds_fence();
  }
#pragma unroll
  for(int s=0;s<5;s++){
#pragma unroll
    for(int r=0;r<4;r++) red[w][q*4+r][c16] = acc[s][r];
    __syncthreads();
    if(w==0){
      float* base = sc + (size_t)s*13*NPTS;
#pragma unroll
      for(int r=0;r<4;r++){
        int m = q*4+r, i = i0+m;
        float D = red[0][m][c16]+red[1][m][c16]+red[2][m][c16]+red[3][m][c16];
        if(c16==0)       atomicAdd(&base[i], D);
        else if(c16<4)   atomicAdd(&base[NPTS + i*3 + (c16-1)], D);
        else if(c16<10)  atomicAdd(&base[4*NPTS + i*6 + (c16-4)], D);
        else if(c16<13)  atomicAdd(&base[10*NPTS + i*3 + (c16-10)], D);
      }
    }
    __syncthreads();
  }
}

// ---- k2p: precompute F2[s][c][j] hi/lo -------------------------------------
__global__ __launch_bounds__(256) void k2p(const float* __restrict__ vertsF,
                                           const float* __restrict__ sc,
                                           ushort_t* __restrict__ F2h,
                                           ushort_t* __restrict__ F2l){
  int idx = blockIdx.x*256 + threadIdx.x;
  int j = idx & (NPTS-1);
  int s = idx >> 12;
  float vx=vertsF[j*3+0], vy=vertsF[j*3+1], vz=vertsF[j*3+2];
  const float* ub = sc + (size_t)s*13*NPTS + 10*NPTS + (size_t)j*3;
  float ux=ub[0], uy=ub[1], uz=ub[2];
  float inv = 1.0f/fmaxf(sqrtf(ux*ux+uy*uy+uz*uz), 1e-12f);
  float n0=ux*inv, n1=uy*inv, n2=uz*inv;
  float fv[16];
  fv[0]=n0; fv[1]=n1; fv[2]=n2;
  fv[3]=vx*n0; fv[4]=vx*n1; fv[5]=vx*n2;
  fv[6]=vy*n0; fv[7]=vy*n1; fv[8]=vy*n2;
  fv[9]=vz*n0; fv[10]=vz*n1; fv[11]=vz*n2;
  fv[12]=0.0f; fv[13]=0.0f; fv[14]=0.0f; fv[15]=0.0f;
#pragma unroll
  for(int c=0;c<16;c++){
    unsigned short h=f2bf(fv[c]);
    F2h[((size_t)s*16+c)*NPTS+j]=h;
    F2l[((size_t)s*16+c)*NPTS+j]=f2bf(fv[c]-bf2f(h));
  }
}

// ---- k2m: pass-2 moments; 32-i tile (vq padded to 5) -----------------------
__global__ __launch_bounds__(256) void k2m(const float* __restrict__ vertsF,
                                           const ushort_t* __restrict__ F2h,
                                           const ushort_t* __restrict__ F2l,
                                           float* __restrict__ mom2){
  __shared__ __align__(16) float vq[4][64][5];
  __shared__ float red[4][16][17];
  const float c2e[5] = {0.5f*LOG2E, 0.125f*LOG2E, (1.0f/18.0f)*LOG2E,
                        0.02f*LOG2E, 0.005f*LOG2E};
  int lane = threadIdx.x & 63, w = threadIdx.x >> 6;
  int c16 = lane & 15, q = lane >> 4;
  int it = blockIdx.x >> 3, jseg = blockIdx.x & (JS2-1);
  int iA = it*32 + c16, iB = iA + 16;
  float vax=vertsF[iA*3+0], vay=vertsF[iA*3+1], vaz=vertsF[iA*3+2];
  float nsqA = vax*vax+vay*vay+vaz*vaz;
  float vbx=vertsF[iB*3+0], vby=vertsF[iB*3+1], vbz=vertsF[iB*3+2];
  float nsqB = vbx*vbx+vby*vby+vbz*vbz;
  f32x4v accA[5], accB[5];
#pragma unroll
  for(int s=0;s<5;s++){
    accA[s] = (f32x4v){0.0f,0.0f,0.0f,0.0f};
    accB[s] = (f32x4v){0.0f,0.0f,0.0f,0.0f};
  }

  int jbeg = jseg*(NPTS/JS2) + w*(NPTS/JS2/4);
  int jend = jbeg + (NPTS/JS2/4);
#pragma unroll 1
  for(int jb=jbeg; jb<jend; jb+=64){
    int j = jb + lane;
    float vx=vertsF[j*3+0], vy=vertsF[j*3+1], vz=vertsF[j*3+2];
    vq[w][lane][0]=vx; vq[w][lane][1]=vy; vq[w][lane][2]=vz;
    vq[w][lane][3]=vx*vx+vy*vy+vz*vz;
    wave_lds_fence();
#pragma unroll
    for(int q2=0;q2<2;q2++){
      int rb = jb + q2*32 + q*8;
      float d2A[8], d2B[8];
#pragma unroll
      for(int t=0;t<8;t++){
        const float* vv = &vq[w][q2*32+q*8+t][0];
        float dotA = vax*vv[0] + vay*vv[1] + vaz*vv[2];
        float dotB = vbx*vv[0] + vby*vv[1] + vbz*vv[2];
        d2A[t] = fmaxf(nsqA + vv[3] - 2.0f*dotA, 0.0f);
        d2B[t] = fmaxf(nsqB + vv[3] - 2.0f*dotB, 0.0f);
      }
#pragma unroll
      for(int s=0;s<5;s++){
        bf16x8v bh = *(const bf16x8v*)(F2h + ((size_t)s*16+c16)*NPTS + rb);
        bf16x8v bl = *(const bf16x8v*)(F2l + ((size_t)s*16+c16)*NPTS + rb);
        bf16x8v afA, afB;
#pragma unroll
        for(int t=0;t<8;t++){
          afA[t] = __builtin_bit_cast(__bf16, f2bf(exp2f(-d2A[t]*c2e[s])));
          afB[t] = __builtin_bit_cast(__bf16, f2bf(exp2f(-d2B[t]*c2e[s])));
        }
        accA[s] = __builtin_amdgcn_mfma_f32_16x16x32_bf16(afA, bh, accA[s], 0,0,0);
        accA[s] = __builtin_amdgcn_mfma_f32_16x16x32_bf16(afA, bl, accA[s], 0,0,0);
        accB[s] = __builtin_amdgcn_mfma_f32_16x16x32_bf16(afB, bh, accB[s], 0,0,0);
        accB[s] = __builtin_amdgcn_mfma_f32_16x16x32_bf16(afB, bl, accB[s], 0,0,0);
      }
    }
    wave_lds_fence();
  }
#pragma unroll
  for(int sub=0; sub<2; sub++){
    int ibase = it*32 + sub*16;
#pragma unroll
    for(int s=0;s<5;s++){
#pragma unroll
      for(int r=0;r<4;r++) red[w][q*4+r][c16] = (sub ? accB[s][r] : accA[s][r]);
      __syncthreads();
      if(w==0){
#pragma unroll
        for(int r=0;r<4;r++){
          int m = q*4+r, i = ibase+m;
          float D = red[0][m][c16]+red[1][m][c16]+red[2][m][c16]+red[3][m][c16];
          if(c16<12) atomicAdd(&mom2[((size_t)s*NPTS + i)*12 + c16], D);
        }
      }
      __syncthreads();
    }
  }
}

// ---- k23: curvature solve + os/ni MLPs + GN-in stats -----------------------
__global__ __launch_bounds__(256) void k23(const float* __restrict__ vertsF,
    const float* __restrict__ sc, const float* __restrict__ mom2,
    float* __restrict__ xfF,
    const float* os_w1, const float* os_b1, const float* os_w2, const float* os_b2,
    const float* ni_w1, const float* ni_b1, const float* ni_w2, const float* ni_b2,
    float* __restrict__ wOS, float* __restrict__ hPre, float* __restrict__ stats){
  int i = blockIdx.x*256 + threadIdx.x;
  int lane = threadIdx.x & 63;
  float xf[DINF];
#pragma unroll
  for(int k=0;k<16;k++) xf[k]=xfF[i*DINF+k];
  float v[3] = { vertsF[i*3+0], vertsF[i*3+1], vertsF[i*3+2] };
#pragma unroll 1
  for(int s=0;s<5;s++){
    const float* base = sc + (size_t)s*13*NPTS;
    float s0 = base[i];
    float sx[3] = { base[NPTS+i*3+0], base[NPTS+i*3+1], base[NPTS+i*3+2] };
    float sxx6[6];
#pragma unroll
    for(int k=0;k<6;k++) sxx6[k]=base[4*NPTS+i*6+k];
    float ux=base[10*NPTS+i*3+0], uy=base[10*NPTS+i*3+1], uz=base[10*NPTS+i*3+2];
    float invn = 1.0f/fmaxf(sqrtf(ux*ux+uy*uy+uz*uz), 1e-12f);
    float nsi[3] = { ux*invn, uy*invn, uz*invn };
    const float* M2 = mom2 + ((size_t)s*NPTS + i)*12;
    float sn[3] = { M2[0], M2[1], M2[2] };
    float sxn[3][3];
#pragma unroll
    for(int a=0;a<3;a++)
#pragma unroll
      for(int b=0;b<3;b++) sxn[a][b]=M2[3+a*3+b];
    const int m6[3][3]={{0,1,2},{1,3,4},{2,4,5}};
    float cxx[3][3], cxn[3][3];
#pragma unroll
    for(int a=0;a<3;a++)
#pragma unroll
      for(int b=0;b<3;b++){
        cxx[a][b]=sxx6[m6[a][b]] - v[a]*sx[b] - sx[a]*v[b] + s0*v[a]*v[b];
        cxn[a][b]=sxn[a][b]    - v[a]*sn[b] - sx[a]*nsi[b] + s0*v[a]*nsi[b];
      }
    float t1[3],t2[3];
    tangent(nsi[0],nsi[1],nsi[2],t1,t2);
    float ppt[2][2], pqt[2][2];
#pragma unroll
    for(int k=0;k<2;k++){
      const float* tk = (k==0)?t1:t2;
#pragma unroll
      for(int l=0;l<2;l++){
        const float* tl = (l==0)?t1:t2;
        float accx=0.0f, accn=0.0f;
#pragma unroll
        for(int a=0;a<3;a++)
#pragma unroll
          for(int b=0;b<3;b++){
            accx += tk[a]*cxx[a][b]*tl[b];
            accn += tk[a]*cxn[a][b]*tl[b];
          }
        ppt[k][l]=accx + ((k==l)?0.01f:0.0f);
        pqt[k][l]=accn;
      }
    }
    float det = ppt[0][0]*ppt[1][1]-ppt[0][1]*ppt[1][0];
    float id = 1.0f/det;
    float S00=( ppt[1][1]*pqt[0][0]-ppt[0][1]*pqt[1][0])*id;
    float S01=( ppt[1][1]*pqt[0][1]-ppt[0][1]*pqt[1][1])*id;
    float S10=(-ppt[1][0]*pqt[0][0]+ppt[0][0]*pqt[1][0])*id;
    float S11=(-ppt[1][0]*pqt[0][1]+ppt[0][0]*pqt[1][1])*id;
    float f0=fminf(fmaxf(S00+S11,-1.0f),1.0f);
    float f1=fminf(fmaxf(S00*S11-S01*S10,-1.0f),1.0f);
    xf[16+2*s]=f0; xf[17+2*s]=f1;
    xfF[i*DINF+16+2*s]=f0;
    xfF[i*DINF+17+2*s]=f1;
  }
  float h1[16];
#pragma unroll
  for(int o=0;o<16;o++){
    float t=ldb(os_b1,o);
#pragma unroll
    for(int k=0;k<DINF;k++) t += xf[k]*ldb(os_w1,o*DINF+k);
    h1[o]=lk(t);
  }
  float w=ldb(os_b2,0);
#pragma unroll
  for(int o=0;o<16;o++) w += h1[o]*ldb(os_w2,o);
  wOS[i]=w;
#pragma unroll
  for(int o=0;o<16;o++){
    float t=ldb(ni_b1,o);
#pragma unroll
    for(int k=0;k<DINF;k++) t += xf[k]*ldb(ni_w1,o*DINF+k);
    h1[o]=lk(t);
  }
  float h2[16];
#pragma unroll
  for(int o=0;o<16;o++){
    float t=ldb(ni_b2,o);
#pragma unroll
    for(int k=0;k<16;k++) t += h1[k]*ldb(ni_w2,o*16+k);
    h2[o]=lk(t);
    hPre[i*16+o]=h2[o];
  }
  float gs[4]={0,0,0,0}, gq[4]={0,0,0,0};
#pragma unroll
  for(int c=0;c<16;c++){ gs[c>>2]+=h2[c]; gq[c>>2]+=h2[c]*h2[c]; }
  __shared__ float ls[8];
  if(threadIdx.x<8) ls[threadIdx.x]=0.0f;
  __syncthreads();
#pragma unroll
  for(int g=0;g<4;g++){ gs[g]=wsum64(gs[g]); gq[g]=wsum64(gq[g]); }
  if(lane==0){
#pragma unroll
    for(int g=0;g<4;g++){ atomicAdd(&ls[2*g],gs[g]); atomicAdd(&ls[2*g+1],gq[g]); }
  }
  __syncthreads();
  if(threadIdx.x<8) atomicAdd(&stats[threadIdx.x], ls[threadIdx.x]);
}

// ---- k3c: GN -> hTb  +  B4 hi/lo tables ------------------------------------
__global__ __launch_bounds__(256) void k3c_gn(const float* __restrict__ hPre,
                                              const float* __restrict__ stats,
                                              const float* gw, const float* gb,
                                              const float* __restrict__ pF,
                                              const float* __restrict__ wOS,
                                              ushort_t* __restrict__ hTb,
                                              ushort_t* __restrict__ B4h,
                                              ushort_t* __restrict__ B4l){
  int i = blockIdx.x*256 + threadIdx.x;
  float m[4], r[4];
#pragma unroll
  for(int g=0;g<4;g++){
    float mean = stats[2*g]*(1.0f/(4.0f*NPTS));
    float var  = stats[2*g+1]*(1.0f/(4.0f*NPTS)) - mean*mean;
    m[g]=mean; r[g]=1.0f/sqrtf(var+1e-5f);
  }
#pragma unroll
  for(int c=0;c<16;c++){
    int g=c>>2;
    float v=(hPre[i*16+c]-m[g])*r[g]*ldb(gw,c)+ldb(gb,c);
    hTb[c*NPTS+i]=f2bf(v);
  }
  float wj=wOS[i];
  float fv[16];
  fv[0]=wj*pF[i*3+0]; fv[1]=wj*pF[i*3+1]; fv[2]=wj*pF[i*3+2]; fv[3]=wj;
#pragma unroll
  for(int c=4;c<16;c++) fv[c]=0.0f;
#pragma unroll
  for(int c=0;c<16;c++){
    unsigned short h=f2bf(fv[c]);
    B4h[c*NPTS+i]=h;
    B4l[c*NPTS+i]=f2bf(fv[c]-bf2f(h));
  }
}

// ---- k4m: ov via MFMA (vq padded to 9) -------------------------------------
__global__ __launch_bounds__(512) void k4m(const float* __restrict__ pF,
                                           const float* __restrict__ nF,
                                           const ushort_t* __restrict__ B4h,
                                           const ushort_t* __restrict__ B4l,
                                           float* __restrict__ nuvF){
  __shared__ __align__(16) float vq[8][64][9];
  __shared__ float red[8][16][5];
  int lane = threadIdx.x & 63, w = threadIdx.x >> 6;
  int c16 = lane & 15, q = lane >> 4;
  int i0 = blockIdx.x*16;
  int ia = i0 + c16;
  float pix=pF[ia*3+0], piy=pF[ia*3+1], piz=pF[ia*3+2];
  float nix=nF[ia*3+0], niy=nF[ia*3+1], niz=nF[ia*3+2];
  f32x4v acc = {0.0f,0.0f,0.0f,0.0f};

#pragma unroll 1
  for(int jb=w*512; jb<w*512+512; jb+=64){
    int j = jb + lane;
    vq[w][lane][0]=pF[j*3+0]; vq[w][lane][1]=pF[j*3+1]; vq[w][lane][2]=pF[j*3+2];
    vq[w][lane][4]=nF[j*3+0]; vq[w][lane][5]=nF[j*3+1]; vq[w][lane][6]=nF[j*3+2];
    wave_lds_fence();
#pragma unroll
    for(int q2=0;q2<2;q2++){
      int rb = jb + q2*32 + q*8;
      bf16x8v bh = *(const bf16x8v*)(B4h + c16*NPTS + rb);
      bf16x8v bl = *(const bf16x8v*)(B4l + c16*NPTS + rb);
      bf16x8v af;
#pragma unroll
      for(int t=0;t<8;t++){
        const float* vv = &vq[w][q2*32+q*8+t][0];
        float dx=vv[0]-pix, dy=vv[1]-piy, dz=vv[2]-piz;
        float d2=dx*dx+dy*dy+dz*dz;
        float f=2.0f-(vv[4]*nix+vv[5]*niy+vv[6]*niz);
        af[t]=__builtin_bit_cast(__bf16, f2bf(exp2f(-d2*f*f*LOG2E)));
      }
      acc = __builtin_amdgcn_mfma_f32_16x16x32_bf16(af, bh, acc, 0,0,0);
      acc = __builtin_amdgcn_mfma_f32_16x16x32_bf16(af, bl, acc, 0,0,0);
    }
    wave_lds_fence();
  }
#pragma unroll
  for(int r=0;r<4;r++) if(c16<4) red[w][q*4+r][c16]=acc[r];
  __syncthreads();
  if(threadIdx.x<16){
    int tid=threadIdx.x, i=i0+tid;
    float a0=0,a1=0,a2=0,a3=0;
#pragma unroll
    for(int ww=0;ww<8;ww++){
      a0+=red[ww][tid][0]; a1+=red[ww][tid][1];
      a2+=red[ww][tid][2]; a3+=red[ww][tid][3];
    }
    float pix2=pF[i*3+0], piy2=pF[i*3+1], piz2=pF[i*3+2];
    float nix2=nF[i*3+0], niy2=nF[i*3+1], niz2=nF[i*3+2];
    float o0=a0-a3*pix2, o1=a1-a3*piy2, o2=a2-a3*piz2;
    float t1[3],t2[3];
    tangent(nix2,niy2,niz2,t1,t2);
    float ov0=t1[0]*o0+t1[1]*o1+t1[2]*o2+1e-5f;
    float ov1=t2[0]*o0+t2[1]*o1+t2[2]*o2+1e-5f;
    float inv=1.0f/sqrtf(ov0*ov0+ov1*ov1);
    float ex=ov0*inv, ey=ov1*inv;
    nuvF[i*9+0]=nix2; nuvF[i*9+1]=niy2; nuvF[i*9+2]=niz2;
    nuvF[i*9+3]= ex*t1[0]+ey*t2[0]; nuvF[i*9+4]= ex*t1[1]+ey*t2[1]; nuvF[i*9+5]= ex*t1[2]+ey*t2[2];
    nuvF[i*9+6]=-ey*t1[0]+ex*t2[0]; nuvF[i*9+7]=-ey*t1[1]+ex*t2[1]; nuvF[i*9+8]=-ey*t1[2]+ex*t2[2];
  }
}

// ---- k5: conv, i-as-M (vq padded to 9, red to 5, JK5=8) --------------------
__global__ __launch_bounds__(256) void k5_conv(const float* __restrict__ pF,
                                               const float* __restrict__ nF,
                                               const float* __restrict__ nuvF,
                                               const ushort_t* __restrict__ hTb,
                                               const float* cv_a1, const float* cv_b1,
                                               const float* cv_a2, const float* cv_b2,
                                               float* __restrict__ xiP){
  __shared__ __align__(16) float vq[4][64][9];
  __shared__ float red[4][64][5];
  int lane = threadIdx.x & 63, w = threadIdx.x >> 6;
  int c16 = lane & 15, q = lane >> 4;
  int it = blockIdx.x >> 3, jseg = blockIdx.x & (JK5-1);
  int i0 = it*16;
  int i = i0 + c16;
  float pix=pF[i*3+0], piy=pF[i*3+1], piz=pF[i*3+2];
  float nu[9];
#pragma unroll
  for(int k=0;k<9;k++) nu[k]=nuvF[i*9+k];
  float a1w[8][3], b1w[8];
#pragma unroll
  for(int c=0;c<8;c++){
    a1w[c][0]=cv_a1[c*3+0]; a1w[c][1]=cv_a1[c*3+1]; a1w[c][2]=cv_a1[c*3+2];
    b1w[c]=cv_b1[c];
  }
  f32x4v acc[9];
#pragma unroll
  for(int c=0;c<9;c++) acc[c]=(f32x4v){0.0f,0.0f,0.0f,0.0f};

  int jbeg = jseg*(NPTS/JK5) + w*(NPTS/JK5/4);
  int jend = jbeg + (NPTS/JK5/4);
#pragma unroll 1
  for(int jb=jbeg; jb<jend; jb+=64){
    int j = jb + lane;
    vq[w][lane][0]=pF[j*3+0]; vq[w][lane][1]=pF[j*3+1]; vq[w][lane][2]=pF[j*3+2];
    vq[w][lane][4]=nF[j*3+0]; vq[w][lane][5]=nF[j*3+1]; vq[w][lane][6]=nF[j*3+2];
    wave_lds_fence();
#pragma unroll
    for(int q2=0;q2<2;q2++){
      int rb = jb + q2*32 + q*8;
      bf16x8v bfr = *(const bf16x8v*)(hTb + c16*NPTS + rb);
      bf16x8v af[9];
#pragma unroll
      for(int t=0;t<8;t++){
        const float* vv = &vq[w][q2*32+q*8+t][0];
        float dx=vv[0]-pix, dy=vv[1]-piy, dz=vv[2]-piz;
        float d2=dx*dx+dy*dy+dz*dz;
        float f=2.0f-(vv[4]*nu[0]+vv[5]*nu[1]+vv[6]*nu[2]);
        float win=exp2f(-d2*f*f*LOG2E);
        float X0=nu[0]*dx+nu[1]*dy+nu[2]*dz;
        float X1=nu[3]*dx+nu[4]*dy+nu[5]*dz;
        float X2=nu[6]*dx+nu[7]*dy+nu[8]*dz;
#pragma unroll
        for(int c=0;c<8;c++){
          float r=fmaf(X0,a1w[c][0],fmaf(X1,a1w[c][1],fmaf(X2,a1w[c][2],b1w[c])));
          af[c][t]=__builtin_bit_cast(__bf16, f2bf(win*fmaxf(r,0.0f)));
        }
        af[8][t]=__builtin_bit_cast(__bf16, f2bf(win));
      }
#pragma unroll
      for(int c=0;c<9;c++)
        acc[c] = __builtin_amdgcn_mfma_f32_16x16x32_bf16(af[c], bfr, acc[c], 0,0,0);
    }
    wave_lds_fence();
  }
  float a2row[8];
#pragma unroll
  for(int c=0;c<8;c++) a2row[c]=cv_a2[c16*8+c];
  float b2v = cv_b2[c16];
#pragma unroll
  for(int r=0;r<4;r++){
    float xi = acc[8][r]*b2v;
#pragma unroll
    for(int c=0;c<8;c++) xi += acc[c][r]*a2row[c];
    red[w][lane][r]=xi;
  }
  __syncthreads();
  if(w==0){
#pragma unroll
    for(int r=0;r<4;r++){
      float v = red[0][lane][r]+red[1][lane][r]+red[2][lane][r]+red[3][lane][r];
      xiP[((size_t)jseg*NPTS + (i0 + q*4 + r))*16 + c16] = v;
    }
  }
}

// ---- k6a: sum xiP slices + no-MLP + GN-out stats ---------------------------
__global__ __launch_bounds__(256) void k6a(const float* __restrict__ xiP,
    const float* no_w1, const float* no_b1, const float* no_w2, const float* no_b2,
    float* __restrict__ tF, float* __restrict__ stats2){
  int i = blockIdx.x*256 + threadIdx.x;
  int lane = threadIdx.x & 63;
  float xi[16];
#pragma unroll
  for(int k=0;k<16;k++){
    float v=0.0f;
#pragma unroll
    for(int s=0;s<JK5;s++) v += xiP[((size_t)s*NPTS + i)*16 + k];
    xi[k]=v;
  }
  float t1[16];
#pragma unroll
  for(int o=0;o<16;o++){
    float t=ldb(no_b1,o);
#pragma unroll
    for(int k=0;k<16;k++) t += xi[k]*ldb(no_w1,o*16+k);
    t1[o]=lk(t);
  }
  float t2[16];
#pragma unroll
  for(int o=0;o<16;o++){
    float t=ldb(no_b2,o);
#pragma unroll
    for(int k=0;k<16;k++) t += t1[k]*ldb(no_w2,o*16+k);
    t2[o]=lk(t);
    tF[i*16+o]=t2[o];
  }
  float gs[4]={0,0,0,0}, gq[4]={0,0,0,0};
#pragma unroll
  for(int c=0;c<16;c++){ gs[c>>2]+=t2[c]; gq[c>>2]+=t2[c]*t2[c]; }
  __shared__ float ls[8];
  if(threadIdx.x<8) ls[threadIdx.x]=0.0f;
  __syncthreads();
#pragma unroll
  for(int g=0;g<4;g++){ gs[g]=wsum64(gs[g]); gq[g]=wsum64(gq[g]); }
  if(lane==0){
#pragma unroll
    for(int g=0;g<4;g++){ atomicAdd(&ls[2*g],gs[g]); atomicAdd(&ls[2*g+1],gq[g]); }
  }
  __syncthreads();
  if(threadIdx.x<8) atomicAdd(&stats2[threadIdx.x], ls[threadIdx.x]);
}

// ---- k6c ----
__global__ __launch_bounds__(256) void k6c(const float* __restrict__ tF,
    const float* __restrict__ xfF, const float* __restrict__ stats2,
    const float* gw, const float* gb,
    const float* ll_w1, const float* ll_b1, const float* ll_w2, const float* ll_b2,
    const float* lt_w, const float* lt_b,
    float* __restrict__ out){
  int i = blockIdx.x*256 + threadIdx.x;
  float m[4], r[4];
#pragma unroll
  for(int g=0;g<4;g++){
    float mean = stats2[2*g]*(1.0f/(4.0f*NPTS));
    float var  = stats2[2*g+1]*(1.0f/(4.0f*NPTS)) - mean*mean;
    m[g]=mean; r[g]=1.0f/sqrtf(var+1e-5f);
  }
  float tn[16];
#pragma unroll
  for(int c=0;c<16;c++){
    int g=c>>2;
    tn[c]=(tF[i*16+c]-m[g])*r[g]*ldb(gw,c)+ldb(gb,c);
  }
  float z1[16];
#pragma unroll
  for(int o=0;o<16;o++){
    float t=ldb(ll_b1,o);
#pragma unroll
    for(int k=0;k<16;k++) t += tn[k]*ldb(ll_w1,o*16+k);
    z1[o]=fmaxf(t,0.0f);
  }
  float xf[DINF];
#pragma unroll
  for(int k=0;k<DINF;k++) xf[k]=xfF[i*DINF+k];
#pragma unroll
  for(int o=0;o<16;o++){
    float z=ldb(ll_b2,o);
#pragma unroll
    for(int k=0;k<16;k++) z += z1[k]*ldb(ll_w2,o*16+k);
    float lt=ldb(lt_b,o);
#pragma unroll
    for(int k=0;k<DINF;k++) lt += xf[k]*ldb(lt_w,o*DINF+k);
    out[i*16+o]=z+lt;
  }
}

extern "C" void kernel_launch(void* const* d_in, const int* in_sizes, int n_in,
                              void* d_out, int out_size, void* d_ws, size_t ws_size,
                              hipStream_t stream){
  const float* verts    = (const float*)d_in[0];
  const float* vnormals = (const float*)d_in[1];
  const float* x        = (const float*)d_in[2];
  const float* os_w1    = (const float*)d_in[3];
  const float* os_b1    = (const float*)d_in[4];
  const float* os_w2    = (const float*)d_in[5];
  const float* os_b2    = (const float*)d_in[6];
  const float* ni_w1    = (const float*)d_in[7];
  const float* ni_b1    = (const float*)d_in[8];
  const float* ni_w2    = (const float*)d_in[9];
  const float* ni_b2    = (const float*)d_in[10];
  const float* gn_in_w  = (const float*)d_in[11];
  const float* gn_in_b  = (const float*)d_in[12];
  const float* cv_a1    = (const float*)d_in[13];
  const float* cv_b1    = (const float*)d_in[14];
  const float* cv_a2    = (const float*)d_in[15];
  const float* cv_b2    = (const float*)d_in[16];
  const float* no_w1    = (const float*)d_in[17];
  const float* no_b1    = (const float*)d_in[18];
  const float* no_w2    = (const float*)d_in[19];
  const float* no_b2    = (const float*)d_in[20];
  const float* gn_out_w = (const float*)d_in[21];
  const float* gn_out_b = (const float*)d_in[22];
  const float* ll_w1    = (const float*)d_in[23];
  const float* ll_b1    = (const float*)d_in[24];
  const float* ll_w2    = (const float*)d_in[25];
  const float* ll_b2    = (const float*)d_in[26];
  const float* lt_w     = (const float*)d_in[27];
  const float* lt_b     = (const float*)d_in[28];

  float* W = (float*)d_ws;
  size_t off = 0;
  float* vertsF = W + off; off += (size_t)3*NPTS;
  float* nF     = W + off; off += (size_t)3*NPTS;
  float* pF     = W + off; off += (size_t)3*NPTS;
  float* xfF    = W + off; off += (size_t)DINF*NPTS;
  float* wOS    = W + off; off += (size_t)NPTS;
  float* hPre   = W + off; off += (size_t)16*NPTS;
  ushort_t* hTb = (ushort_t*)(W + off); off += (size_t)8*NPTS;
  float* nuvF   = W + off; off += (size_t)9*NPTS;
  float* xiP    = W + off; off += (size_t)JK5*16*NPTS;
  float* tF     = W + off; off += (size_t)16*NPTS;
  ushort_t* F1h = (ushort_t*)(W + off); off += (size_t)8*NPTS;
  ushort_t* F1l = (ushort_t*)(W + off); off += (size_t)8*NPTS;
  ushort_t* F2h = (ushort_t*)(W + off); off += (size_t)40*NPTS;
  ushort_t* F2l = (ushort_t*)(W + off); off += (size_t)40*NPTS;
  ushort_t* B4h = (ushort_t*)(W + off); off += (size_t)8*NPTS;
  ushort_t* B4l = (ushort_t*)(W + off); off += (size_t)8*NPTS;
  float* zr     = W + off;
  float* sc     = W + off; off += (size_t)13*NPTS*5;
  float* mom2   = W + off; off += (size_t)12*NPTS*5;
  float* stats  = W + off; off += 16;
  size_t zbytes = ((size_t)13*NPTS*5 + (size_t)12*NPTS*5 + 16)*sizeof(float);

  hipMemsetAsync(zr, 0, zbytes, stream);

  k0_convert<<<NPTS/256, 256, 0, stream>>>(verts, vnormals, x, vertsF, nF, pF, xfF,
                                           F1h, F1l);
  k1m<<<(NPTS/16)*JSPL, 256, 0, stream>>>(vertsF, F1h, F1l, sc);
  k2p<<<5*NPTS/256, 256, 0, stream>>>(vertsF, sc, F2h, F2l);
  k2m<<<(NPTS/32)*JS2, 256, 0, stream>>>(vertsF, F2h, F2l, mom2);
  k23<<<NPTS/256, 256, 0, stream>>>(vertsF, sc, mom2, xfF,
                                    os_w1, os_b1, os_w2, os_b2,
                                    ni_w1, ni_b1, ni_w2, ni_b2, wOS, hPre, stats);
  k3c_gn<<<NPTS/256, 256, 0, stream>>>(hPre, stats, gn_in_w, gn_in_b,
                                       pF, wOS, hTb, B4h, B4l);
  k4m<<<NPTS/16, 512, 0, stream>>>(pF, nF, B4h, B4l, nuvF);
  k5_conv<<<(NPTS/16)*JK5, 256, 0, stream>>>(pF, nF, nuvF, hTb,
                                             cv_a1, cv_b1, cv_a2, cv_b2, xiP);
  k6a<<<NPTS/256, 256, 0, stream>>>(xiP, no_w1, no_b1, no_w2, no_b2, tF, stats+8);
  k6c<<<NPTS/256, 256, 0, stream>>>(tF, xfF, stats+8, gn_out_w, gn_out_b,
                                    ll_w1, ll_b1, ll_w2, ll_b2, lt_w, lt_b, (float*)d_out);
}